// Round 4
// baseline (830.387 us; speedup 1.0000x reference)
//
#include <hip/hip_runtime.h>
#include <hip/hip_bf16.h>

#define NN 100000
#define EE 800000
#define HH 4
#define CC 64
#define GG 2000
#define NB 98           // scan blocks: ceil((NN/4)/256)

typedef unsigned short ushortx;
typedef __attribute__((ext_vector_type(8))) short short8;
typedef __attribute__((ext_vector_type(4))) float f32x4;

// ---------------- CSR build ----------------

__global__ void hist_kernel(const int* __restrict__ ei, int* __restrict__ deg) {
    int e = blockIdx.x * 256 + threadIdx.x;
    const int tot = EE + NN;
    if (e < tot) {
        int d = (e < EE) ? ei[EE + e] : (e - EE);
        atomicAdd(&deg[d], 1);
    }
}

__global__ void node_count(const int* __restrict__ batch, float* __restrict__ pcnt) {
    int n = blockIdx.x * 256 + threadIdx.x;
    if (n < NN) atomicAdd(&pcnt[batch[n]], 1.0f);
}

__global__ __launch_bounds__(256) void scan_blk(const int* __restrict__ deg,
                                                int* __restrict__ bsum) {
    const int t = threadIdx.x;
    const int idx4 = blockIdx.x * 256 + t;
    int4 v = {0, 0, 0, 0};
    if (idx4 < NN / 4) v = ((const int4*)deg)[idx4];
    int s = v.x + v.y + v.z + v.w;
#pragma unroll
    for (int m = 32; m; m >>= 1) s += __shfl_xor(s, m, 64);
    __shared__ int ws[4];
    if ((t & 63) == 0) ws[t >> 6] = s;
    __syncthreads();
    if (t == 0) bsum[blockIdx.x] = ws[0] + ws[1] + ws[2] + ws[3];
}

__global__ void scan_mid(const int* __restrict__ bsum, int* __restrict__ boff,
                         int* __restrict__ off) {
    __shared__ int sh[128];
    const int t = threadIdx.x;
    int v = (t < NB) ? bsum[t] : 0;
    sh[t] = v;
    __syncthreads();
    for (int d = 1; d < 128; d <<= 1) {
        int u = (t >= d) ? sh[t - d] : 0;
        __syncthreads();
        sh[t] += u;
        __syncthreads();
    }
    if (t < NB) boff[t] = sh[t] - v;
    if (t == NB - 1) off[NN] = sh[t];
}

__global__ __launch_bounds__(256) void scan_fin(const int* __restrict__ deg,
                                                const int* __restrict__ boff,
                                                int* __restrict__ off) {
    const int t = threadIdx.x;
    const int idx4 = blockIdx.x * 256 + t;
    int4 v = {0, 0, 0, 0};
    if (idx4 < NN / 4) v = ((const int4*)deg)[idx4];
    int s = v.x + v.y + v.z + v.w;
    const int lane = t & 63, w = t >> 6;
    int inc = s;
#pragma unroll
    for (int d = 1; d < 64; d <<= 1) {
        int u = __shfl_up(inc, d, 64);
        if (lane >= d) inc += u;
    }
    __shared__ int ws[4];
    if (lane == 63) ws[w] = inc;
    __syncthreads();
    int woff = 0;
    for (int i = 0; i < w; ++i) woff += ws[i];
    int excl = inc - s + woff + boff[blockIdx.x];
    if (idx4 < NN / 4) {
        int4 o;
        o.x = excl;
        o.y = o.x + v.x;
        o.z = o.y + v.y;
        o.w = o.z + v.z;
        ((int4*)off)[idx4] = o;
    }
}

__global__ void fill_kernel(const int* __restrict__ ei, const int* __restrict__ off,
                            int* __restrict__ cursor, int* __restrict__ csr_src) {
    int e = blockIdx.x * 256 + threadIdx.x;
    const int tot = EE + NN;
    if (e < tot) {
        int s, d;
        if (e < EE) { s = ei[e]; d = ei[EE + e]; }
        else        { s = e - EE; d = e - EE; }
        int p = off[d] + atomicAdd(&cursor[d], 1);
        csr_src[p] = s;
    }
}

__device__ __forceinline__ ushortx f2bf(float v) {
    __hip_bfloat16 b = __float2bfloat16(v);
    return *reinterpret_cast<ushortx*>(&b);
}

// ---------------- attention-vector precompute ----------------
// va[k][comp] with comp = sd*4 + h:  va_s = W @ a_s per head (and a_d).
// al_s[n,h] = x[n,:] . va[:,h]  (pure reassociation of the reference sum).

__global__ void prep_va(const float* __restrict__ W, const float* __restrict__ as_,
                        const float* __restrict__ ad_, float* __restrict__ va,
                        int K) {
    int id = blockIdx.x * 256 + threadIdx.x;
    if (id >= K * 8) return;
    int k = id >> 3, comp = id & 7;
    int h = comp & 3, sd = comp >> 2;
    const float* a = sd ? ad_ : as_;
    const float* wrow = W + k * 256 + h * 64;
    const float* arow = a + h * 64;
    float s = 0.f;
    for (int c = 0; c < 64; ++c) s = fmaf(wrow[c], arow[c], s);
    va[k * 8 + comp] = s;
}

// ALS/ALD from fp32 X (layer 1, K=9): thread = node, va broadcast from LDS.
template <int K>
__global__ __launch_bounds__(256) void att_gemv(
    const float* __restrict__ X, const float* __restrict__ va,
    float* __restrict__ ALS, float* __restrict__ ALD) {
    __shared__ float vs[K][8];
    const int tid = threadIdx.x;
    for (int i = tid; i < K * 8; i += 256) vs[i >> 3][i & 7] = va[i];
    __syncthreads();
    int n = blockIdx.x * 256 + tid;
    if (n >= NN) return;
    const float* xp = X + (size_t)n * K;
    float s0 = 0, s1 = 0, s2 = 0, s3 = 0, d0 = 0, d1 = 0, d2 = 0, d3 = 0;
#pragma unroll
    for (int k = 0; k < K; ++k) {
        float x1 = xp[k];
        const float4 vsv = *(const float4*)&vs[k][0];
        const float4 vdv = *(const float4*)&vs[k][4];
        s0 = fmaf(x1, vsv.x, s0); s1 = fmaf(x1, vsv.y, s1);
        s2 = fmaf(x1, vsv.z, s2); s3 = fmaf(x1, vsv.w, s3);
        d0 = fmaf(x1, vdv.x, d0); d1 = fmaf(x1, vdv.y, d1);
        d2 = fmaf(x1, vdv.z, d2); d3 = fmaf(x1, vdv.w, d3);
    }
    float4 so = {s0, s1, s2, s3}, dd = {d0, d1, d2, d3};
    ((float4*)ALS)[n] = so;
    ((float4*)ALD)[n] = dd;
}

// ALS/ALD from bf16 X (layers 2,3, K=64).
__global__ __launch_bounds__(256) void att_gemv_b(
    const ushortx* __restrict__ Xb, const float* __restrict__ va,
    float* __restrict__ ALS, float* __restrict__ ALD) {
    __shared__ float vs[64][8];
    const int tid = threadIdx.x;
    for (int i = tid; i < 64 * 8; i += 256) vs[i >> 3][i & 7] = va[i];
    __syncthreads();
    int n = blockIdx.x * 256 + tid;
    if (n >= NN) return;
    const uint4* xp = (const uint4*)(Xb + (size_t)n * 64);
    float s0 = 0, s1 = 0, s2 = 0, s3 = 0, d0 = 0, d1 = 0, d2 = 0, d3 = 0;
#pragma unroll
    for (int qq = 0; qq < 8; ++qq) {
        uint4 u = xp[qq];
        float xv[8];
        xv[0] = __uint_as_float(u.x << 16);
        xv[1] = __uint_as_float(u.x & 0xFFFF0000u);
        xv[2] = __uint_as_float(u.y << 16);
        xv[3] = __uint_as_float(u.y & 0xFFFF0000u);
        xv[4] = __uint_as_float(u.z << 16);
        xv[5] = __uint_as_float(u.z & 0xFFFF0000u);
        xv[6] = __uint_as_float(u.w << 16);
        xv[7] = __uint_as_float(u.w & 0xFFFF0000u);
#pragma unroll
        for (int j = 0; j < 8; ++j) {
            const int k = qq * 8 + j;
            const float4 vsv = *(const float4*)&vs[k][0];
            const float4 vdv = *(const float4*)&vs[k][4];
            s0 = fmaf(xv[j], vsv.x, s0); s1 = fmaf(xv[j], vsv.y, s1);
            s2 = fmaf(xv[j], vsv.z, s2); s3 = fmaf(xv[j], vsv.w, s3);
            d0 = fmaf(xv[j], vdv.x, d0); d1 = fmaf(xv[j], vdv.y, d1);
            d2 = fmaf(xv[j], vdv.z, d2); d3 = fmaf(xv[j], vdv.w, d3);
        }
    }
    float4 so = {s0, s1, s2, s3}, dd = {d0, d1, d2, d3};
    ((float4*)ALS)[n] = so;
    ((float4*)ALD)[n] = dd;
}

// ---------------- layer-1: aggregate raw x (K=9, fp32 exact) ---------------
// (A_h x) gathered directly: 36 B/edge instead of 512 B/edge; x (3.6 MB) is
// L2-resident. Lane l: h=l>>4, k=l&15 (active k<9). Output AGG1[n][h*16+k].

__global__ __launch_bounds__(256) void aggregate_x1(
    const float* __restrict__ X, const float* __restrict__ ALS,
    const float* __restrict__ ALD, const int* __restrict__ off,
    const int* __restrict__ csr_src, float* __restrict__ AGG1) {
    __shared__ float2 wtab[4][4][66];      // [wave][head][edge(padded)]
    const int wv = threadIdx.x >> 6;
    const int node = blockIdx.x * 4 + wv;
    const int l = threadIdx.x & 63;
    if (node >= NN) return;
    const int beg = off[node], end = off[node + 1];
    const int h = l >> 4, kg = l & 15;
    const bool act = (kg < 9);
    const float4 aldv = ((const float4*)ALD)[node];
    const float2* wt2 = &wtab[wv][h][0];
    float acc = 0.f;
    float den = 0.f;

    for (int j0 = beg; j0 < end; j0 += 64) {
        const int cnt = min(64, end - j0);
        const int jj = j0 + l;
        int sv = 0;
        float4 w4 = {0.f, 0.f, 0.f, 0.f};
        if (jj < end) {
            sv = csr_src[jj];
            float4 a = ((const float4*)ALS)[sv];
            float vx = a.x + aldv.x, vy = a.y + aldv.y,
                  vz = a.z + aldv.z, vw = a.w + aldv.w;
            vx = (vx >= 0.f) ? vx : 0.2f * vx;
            vy = (vy >= 0.f) ? vy : 0.2f * vy;
            vz = (vz >= 0.f) ? vz : 0.2f * vz;
            vw = (vw >= 0.f) ? vw : 0.2f * vw;
            w4.x = __expf(vx); w4.y = __expf(vy);
            w4.z = __expf(vz); w4.w = __expf(vw);
        }
        const float fsv = __int_as_float(sv);
        wtab[wv][0][l] = make_float2(w4.x, fsv);
        wtab[wv][1][l] = make_float2(w4.y, fsv);
        wtab[wv][2][l] = make_float2(w4.z, fsv);
        wtab[wv][3][l] = make_float2(w4.w, fsv);
        __builtin_amdgcn_wave_barrier();
        asm volatile("s_waitcnt lgkmcnt(0)" ::: "memory");
        __builtin_amdgcn_sched_barrier(0);

        int t = 0;
        for (; t + 8 <= cnt; t += 8) {
            const float4 p01 = *(const float4*)&wt2[t];
            const float4 p23 = *(const float4*)&wt2[t + 2];
            const float4 p45 = *(const float4*)&wt2[t + 4];
            const float4 p67 = *(const float4*)&wt2[t + 6];
            float v0 = 0, v1 = 0, v2 = 0, v3 = 0, v4 = 0, v5 = 0, v6 = 0, v7 = 0;
            if (act) {
                v0 = X[(size_t)__float_as_int(p01.y) * 9 + kg];
                v1 = X[(size_t)__float_as_int(p01.w) * 9 + kg];
                v2 = X[(size_t)__float_as_int(p23.y) * 9 + kg];
                v3 = X[(size_t)__float_as_int(p23.w) * 9 + kg];
                v4 = X[(size_t)__float_as_int(p45.y) * 9 + kg];
                v5 = X[(size_t)__float_as_int(p45.w) * 9 + kg];
                v6 = X[(size_t)__float_as_int(p67.y) * 9 + kg];
                v7 = X[(size_t)__float_as_int(p67.w) * 9 + kg];
            }
            den += ((p01.x + p01.z) + (p23.x + p23.z)) +
                   ((p45.x + p45.z) + (p67.x + p67.z));
            acc = fmaf(p01.x, v0, acc); acc = fmaf(p01.z, v1, acc);
            acc = fmaf(p23.x, v2, acc); acc = fmaf(p23.z, v3, acc);
            acc = fmaf(p45.x, v4, acc); acc = fmaf(p45.z, v5, acc);
            acc = fmaf(p67.x, v6, acc); acc = fmaf(p67.z, v7, acc);
        }
        for (; t < cnt; t += 4) {
            const int t1 = min(t + 1, cnt - 1);
            const int t2 = min(t + 2, cnt - 1);
            const int t3 = min(t + 3, cnt - 1);
            float2 e0 = wt2[t], e1 = wt2[t1], e2 = wt2[t2], e3 = wt2[t3];
            float w0 = e0.x;
            float w1v = (t + 1 < cnt) ? e1.x : 0.f;
            float w2v = (t + 2 < cnt) ? e2.x : 0.f;
            float w3v = (t + 3 < cnt) ? e3.x : 0.f;
            float v0 = 0, v1 = 0, v2 = 0, v3 = 0;
            if (act) {
                v0 = X[(size_t)__float_as_int(e0.y) * 9 + kg];
                v1 = X[(size_t)__float_as_int(e1.y) * 9 + kg];
                v2 = X[(size_t)__float_as_int(e2.y) * 9 + kg];
                v3 = X[(size_t)__float_as_int(e3.y) * 9 + kg];
            }
            den += ((w0 + w1v) + (w2v + w3v));
            acc = fmaf(w0, v0, acc); acc = fmaf(w1v, v1, acc);
            acc = fmaf(w2v, v2, acc); acc = fmaf(w3v, v3, acc);
        }
        __builtin_amdgcn_wave_barrier();
    }

    const float inv = 1.f / (den + 1e-16f);
    AGG1[(size_t)node * 64 + l] = act ? acc * inv : 0.f;
}

// ---------------- layer-1 recovery GEMM: out = relu(1/4 AGG1.Wc + b) -------
// K=36 (4 heads x 9), fp32 exact. out[n,c] stored bf16 for next layer.

__global__ __launch_bounds__(256) void gemm36(
    const float* __restrict__ AGG1, const float* __restrict__ W1,
    const float* __restrict__ b1, ushortx* __restrict__ Xb) {
    const int c = threadIdx.x & 63;
    const int wv = threadIdx.x >> 6;
    float wreg[36];
#pragma unroll
    for (int h = 0; h < 4; ++h)
#pragma unroll
        for (int k = 0; k < 9; ++k)
            wreg[h * 9 + k] = W1[k * 256 + h * 64 + c] * 0.25f;
    const float bc = b1[c];
    for (int row = blockIdx.x * 4 + wv; row < NN; row += gridDim.x * 4) {
        const float* xr = AGG1 + (size_t)row * 64;
        float s = 0.f;
#pragma unroll
        for (int h = 0; h < 4; ++h)
#pragma unroll
            for (int k = 0; k < 9; ++k)
                s = fmaf(wreg[h * 9 + k], xr[h * 16 + k], s);
        s = fmaxf(s + bc, 0.f);
        Xb[(size_t)row * 64 + c] = f2bf(s);
    }
}

// ---------------- layers 2,3: aggregate bf16 X (K=64) ----------------------
// Gathers 128 B/edge (X row) instead of 512 B (H row): 4 lane-groups (heads)
// read the SAME 128 B line with different weights; coalescer dedups to one
// line/edge. Working set 12.8 MB (vs 51.2) -> better L2 hit rate. Output
// AGG[n][h*64+kg*4+r] bf16 = AGG[n*256 + l*4] (per-head normalized); head
// mean + bias + relu move into the recovery GEMM. No epilogue reduction.

__global__ __launch_bounds__(256) void aggregate_xb(
    const ushortx* __restrict__ Xb, const float* __restrict__ ALS,
    const float* __restrict__ ALD, const int* __restrict__ off,
    const int* __restrict__ csr_src, ushortx* __restrict__ AGG) {
    __shared__ float2 wtab[4][4][66];      // [wave][head][edge(padded)]
    const int wv = threadIdx.x >> 6;
    const int node = blockIdx.x * 4 + wv;
    const int l = threadIdx.x & 63;
    if (node >= NN) return;
    const int beg = off[node], end = off[node + 1];
    const int h = l >> 4, kg = l & 15;
    const uint2* xb2 = (const uint2*)Xb;   // row = 16 uint2 (64 bf16)
    const float4 aldv = ((const float4*)ALD)[node];
    const float2* wt2 = &wtab[wv][h][0];
    float4 acc = {0.f, 0.f, 0.f, 0.f};
    float den = 0.f;

#define ACC4(uu, ww)                                                \
    {                                                               \
        float c0 = __uint_as_float((uu).x << 16);                   \
        float c1 = __uint_as_float((uu).x & 0xFFFF0000u);           \
        float c2 = __uint_as_float((uu).y << 16);                   \
        float c3 = __uint_as_float((uu).y & 0xFFFF0000u);           \
        acc.x = fmaf((ww), c0, acc.x);                              \
        acc.y = fmaf((ww), c1, acc.y);                              \
        acc.z = fmaf((ww), c2, acc.z);                              \
        acc.w = fmaf((ww), c3, acc.w);                              \
    }

    for (int j0 = beg; j0 < end; j0 += 64) {
        const int cnt = min(64, end - j0);
        const int jj = j0 + l;
        int sv = 0;
        float4 w4 = {0.f, 0.f, 0.f, 0.f};
        if (jj < end) {
            sv = csr_src[jj];
            float4 a = ((const float4*)ALS)[sv];
            float vx = a.x + aldv.x, vy = a.y + aldv.y,
                  vz = a.z + aldv.z, vw = a.w + aldv.w;
            vx = (vx >= 0.f) ? vx : 0.2f * vx;
            vy = (vy >= 0.f) ? vy : 0.2f * vy;
            vz = (vz >= 0.f) ? vz : 0.2f * vz;
            vw = (vw >= 0.f) ? vw : 0.2f * vw;
            w4.x = __expf(vx); w4.y = __expf(vy);
            w4.z = __expf(vz); w4.w = __expf(vw);
        }
        const float fsv = __int_as_float(sv);
        wtab[wv][0][l] = make_float2(w4.x, fsv);
        wtab[wv][1][l] = make_float2(w4.y, fsv);
        wtab[wv][2][l] = make_float2(w4.z, fsv);
        wtab[wv][3][l] = make_float2(w4.w, fsv);
        __builtin_amdgcn_wave_barrier();
        asm volatile("s_waitcnt lgkmcnt(0)" ::: "memory");
        __builtin_amdgcn_sched_barrier(0);

        int t = 0;
        for (; t + 8 <= cnt; t += 8) {
            const float4 p01 = *(const float4*)&wt2[t];
            const float4 p23 = *(const float4*)&wt2[t + 2];
            const float4 p45 = *(const float4*)&wt2[t + 4];
            const float4 p67 = *(const float4*)&wt2[t + 6];
            uint2 u0 = xb2[(size_t)__float_as_int(p01.y) * 16 + kg];
            uint2 u1 = xb2[(size_t)__float_as_int(p01.w) * 16 + kg];
            uint2 u2 = xb2[(size_t)__float_as_int(p23.y) * 16 + kg];
            uint2 u3 = xb2[(size_t)__float_as_int(p23.w) * 16 + kg];
            uint2 u4 = xb2[(size_t)__float_as_int(p45.y) * 16 + kg];
            uint2 u5 = xb2[(size_t)__float_as_int(p45.w) * 16 + kg];
            uint2 u6 = xb2[(size_t)__float_as_int(p67.y) * 16 + kg];
            uint2 u7 = xb2[(size_t)__float_as_int(p67.w) * 16 + kg];
            den += ((p01.x + p01.z) + (p23.x + p23.z)) +
                   ((p45.x + p45.z) + (p67.x + p67.z));
            ACC4(u0, p01.x);
            ACC4(u1, p01.z);
            ACC4(u2, p23.x);
            ACC4(u3, p23.z);
            ACC4(u4, p45.x);
            ACC4(u5, p45.z);
            ACC4(u6, p67.x);
            ACC4(u7, p67.z);
        }
        for (; t < cnt; t += 4) {
            const int t1 = min(t + 1, cnt - 1);
            const int t2 = min(t + 2, cnt - 1);
            const int t3 = min(t + 3, cnt - 1);
            float2 e0 = wt2[t], e1 = wt2[t1], e2 = wt2[t2], e3 = wt2[t3];
            float w0 = e0.x;
            float w1v = (t + 1 < cnt) ? e1.x : 0.f;
            float w2v = (t + 2 < cnt) ? e2.x : 0.f;
            float w3v = (t + 3 < cnt) ? e3.x : 0.f;
            uint2 u0 = xb2[(size_t)__float_as_int(e0.y) * 16 + kg];
            uint2 u1 = xb2[(size_t)__float_as_int(e1.y) * 16 + kg];
            uint2 u2 = xb2[(size_t)__float_as_int(e2.y) * 16 + kg];
            uint2 u3 = xb2[(size_t)__float_as_int(e3.y) * 16 + kg];
            den += ((w0 + w1v) + (w2v + w3v));
            ACC4(u0, w0);
            ACC4(u1, w1v);
            ACC4(u2, w2v);
            ACC4(u3, w3v);
        }
        __builtin_amdgcn_wave_barrier();
    }
#undef ACC4

    const float inv = 1.f / (den + 1e-16f);
    uint p0 = (uint)f2bf(acc.x * inv) | ((uint)f2bf(acc.y * inv) << 16);
    uint p1 = (uint)f2bf(acc.z * inv) | ((uint)f2bf(acc.w * inv) << 16);
    uint2 ov = {p0, p1};
    *(uint2*)&AGG[(size_t)node * 256 + (size_t)l * 4] = ov;
}

// ---------------- recovery GEMM (K=256) on matrix cores --------------------
// out[n,c] = relu(sum_{h,k} AGG[n,h*64+k] * W[k,h*64+c]/4 + b[c]).
// Clones the VERIFIED swapped-operand plumbing of the old gemm64_mfma:
// b-frag wt[ct][kb][l][j] = Wc[kb*32 + (l>>4)*8 + j][ct*16 + (l&15)],
// a-frag = AGG[(row0+(l&15))*256 + kb*32 + (l>>4)*8 + j] (bf16, direct from
// global), mfma(b,a) -> lane holds OUT[row0+(l&15)][ct*16+(l>>4)*4+r].
// LAST=false: store bf16 X for next layer. LAST=true: fused mean-pool atomics.

template <bool LAST>
__global__ __launch_bounds__(256) void gemm256_mfma(
    const ushortx* __restrict__ AGG, const float* __restrict__ W,
    const float* __restrict__ bias, ushortx* __restrict__ Xb,
    const int* __restrict__ batch, float* __restrict__ psum) {
    __shared__ ushortx wt[4][8][64][8];    // [ct][kb][lane][j]  (32 KB)
    const int tid = threadIdx.x;
    const int l = tid & 63, wv = tid >> 6;
    const int n = l & 15, q = l >> 4;

    for (int i = tid; i < 256 * 64; i += 256) {
        int kap = i >> 6, c = i & 63;
        int h = kap >> 6, kw = kap & 63;
        float v = W[kw * 256 + h * 64 + c] * 0.25f;
        int kb = kap >> 5, qq = (kap >> 3) & 3, jj = kap & 7;
        wt[c >> 4][kb][qq * 16 + (c & 15)][jj] = f2bf(v);
    }
    __syncthreads();

    for (int row0 = blockIdx.x * 64 + wv * 16; row0 < NN; row0 += gridDim.x * 64) {
        f32x4 acc[4] = {{0.f, 0.f, 0.f, 0.f}, {0.f, 0.f, 0.f, 0.f},
                        {0.f, 0.f, 0.f, 0.f}, {0.f, 0.f, 0.f, 0.f}};
#pragma unroll
        for (int kb = 0; kb < 8; ++kb) {
            short8 a = *(const short8*)&AGG[(size_t)(row0 + n) * 256 + kb * 32 + q * 8];
#pragma unroll
            for (int ct = 0; ct < 4; ++ct) {
                short8 b = *(const short8*)&wt[ct][kb][l][0];
                acc[ct] = __builtin_amdgcn_mfma_f32_16x16x32_bf16(b, a, acc[ct], 0, 0, 0);
            }
        }
        const int row = row0 + n;
#pragma unroll
        for (int ct = 0; ct < 4; ++ct) {
            const int col = ct * 16 + q * 4;
            float4 b4 = ((const float4*)bias)[ct * 4 + q];
            float o0 = fmaxf(acc[ct][0] + b4.x, 0.f);
            float o1 = fmaxf(acc[ct][1] + b4.y, 0.f);
            float o2 = fmaxf(acc[ct][2] + b4.z, 0.f);
            float o3 = fmaxf(acc[ct][3] + b4.w, 0.f);
            if constexpr (LAST) {
                int g = batch[row];
                float* pp = psum + (size_t)g * 64 + col;
                atomicAdd(pp + 0, o0);
                atomicAdd(pp + 1, o1);
                atomicAdd(pp + 2, o2);
                atomicAdd(pp + 3, o3);
            } else {
                uint p0 = (uint)f2bf(o0) | ((uint)f2bf(o1) << 16);
                uint p1 = (uint)f2bf(o2) | ((uint)f2bf(o3) << 16);
                uint2 ov = {p0, p1};
                *(uint2*)&Xb[(size_t)row * 64 + col] = ov;
            }
        }
    }
}

// ---------------- final linear ----------------

__global__ void pool_out(const float* __restrict__ psum, const float* __restrict__ pcnt,
                         const float* __restrict__ lw, const float* __restrict__ lb,
                         float* __restrict__ out) {
    int g = blockIdx.x * 4 + (threadIdx.x >> 6);
    int lane = threadIdx.x & 63;
    if (g < GG) {
        float cnt = fmaxf(pcnt[g], 1.0f);
        float v = psum[(size_t)g * 64 + lane] / cnt * lw[lane];
#pragma unroll
        for (int m = 32; m; m >>= 1) v += __shfl_xor(v, m, 64);
        if (lane == 0) out[g] = v + lb[0];
    }
}

// ---------------- launch ----------------

extern "C" void kernel_launch(void* const* d_in, const int* in_sizes, int n_in,
                              void* d_out, int out_size, void* d_ws, size_t ws_size,
                              hipStream_t stream) {
    const float* x     = (const float*)d_in[0];
    const int*   ei    = (const int*)d_in[1];
    const int*   batch = (const int*)d_in[2];
    const float* W1  = (const float*)d_in[3];
    const float* as1 = (const float*)d_in[4];
    const float* ad1 = (const float*)d_in[5];
    const float* b1  = (const float*)d_in[6];
    const float* W2  = (const float*)d_in[7];
    const float* as2 = (const float*)d_in[8];
    const float* ad2 = (const float*)d_in[9];
    const float* b2  = (const float*)d_in[10];
    const float* W3  = (const float*)d_in[11];
    const float* as3 = (const float*)d_in[12];
    const float* ad3 = (const float*)d_in[13];
    const float* b3  = (const float*)d_in[14];
    const float* lw  = (const float*)d_in[15];
    const float* lb  = (const float*)d_in[16];
    float* out = (float*)d_out;

    char* p = (char*)d_ws;
    auto carve = [&](size_t bytes) -> void* {
        void* r = (void*)p;
        p += (bytes + 255) & ~(size_t)255;
        return r;
    };
    int*     off    = (int*)carve((NN + 4) * sizeof(int));
    int*     deg    = (int*)carve(NN * sizeof(int));
    int*     cursor = (int*)carve(NN * sizeof(int));
    int*     bsum   = (int*)carve(NB * sizeof(int));
    int*     boff   = (int*)carve(NB * sizeof(int));
    int*     csr    = (int*)carve((size_t)(EE + NN) * sizeof(int));
    ushortx* aggb   = (ushortx*)carve((size_t)NN * 256 * sizeof(ushortx));  // 51.2 MB
    float*   agg1   = (float*)carve((size_t)NN * 64 * sizeof(float));       // 25.6 MB
    ushortx* xb1    = (ushortx*)carve((size_t)NN * 64 * sizeof(ushortx));   // 12.8 MB
    float*   als    = (float*)carve((size_t)NN * 4 * sizeof(float));
    float*   ald    = (float*)carve((size_t)NN * 4 * sizeof(float));
    float*   psum   = (float*)carve((size_t)GG * 64 * sizeof(float));
    float*   pcnt   = (float*)carve(GG * sizeof(float));
    float*   va1    = (float*)carve(9 * 8 * sizeof(float));
    float*   va2    = (float*)carve(64 * 8 * sizeof(float));
    float*   va3    = (float*)carve(64 * 8 * sizeof(float));
    // xb2 aliases agg1 (agg1 is dead after gemm36; xb2 first written in L2 GEMM)
    ushortx* xb2 = (ushortx*)agg1;

    hipMemsetAsync(deg, 0, NN * sizeof(int), stream);
    hipMemsetAsync(cursor, 0, NN * sizeof(int), stream);
    hipMemsetAsync(psum, 0, (size_t)GG * 64 * sizeof(float), stream);
    hipMemsetAsync(pcnt, 0, GG * sizeof(float), stream);

    const int etot = EE + NN;
    const int eblocks = (etot + 255) / 256;
    hist_kernel<<<eblocks, 256, 0, stream>>>(ei, deg);
    node_count<<<(NN + 255) / 256, 256, 0, stream>>>(batch, pcnt);
    scan_blk<<<NB, 256, 0, stream>>>(deg, bsum);
    scan_mid<<<1, 128, 0, stream>>>(bsum, boff, off);
    scan_fin<<<NB, 256, 0, stream>>>(deg, boff, off);
    fill_kernel<<<eblocks, 256, 0, stream>>>(ei, off, cursor, csr);

    prep_va<<<1, 256, 0, stream>>>(W1, as1, ad1, va1, 9);
    prep_va<<<2, 256, 0, stream>>>(W2, as2, ad2, va2, 64);
    prep_va<<<2, 256, 0, stream>>>(W3, as3, ad3, va3, 64);

    const int ablocks = (NN + 3) / 4;
    const int nblocks = (NN + 255) / 256;
    const int gblocks = (NN + 63) / 64;

    // layer 1 (fp32 exact: aggregate x, then K=36 GEMM)
    att_gemv<9><<<nblocks, 256, 0, stream>>>(x, va1, als, ald);
    aggregate_x1<<<ablocks, 256, 0, stream>>>(x, als, ald, off, csr, agg1);
    gemm36<<<2048, 256, 0, stream>>>(agg1, W1, b1, xb1);

    // layer 2
    att_gemv_b<<<nblocks, 256, 0, stream>>>(xb1, va2, als, ald);
    aggregate_xb<<<ablocks, 256, 0, stream>>>(xb1, als, ald, off, csr, aggb);
    gemm256_mfma<false><<<gblocks, 256, 0, stream>>>(aggb, W2, b2, xb2,
                                                     nullptr, nullptr);

    // layer 3 (pooling fused into GEMM epilogue)
    att_gemv_b<<<nblocks, 256, 0, stream>>>(xb2, va3, als, ald);
    aggregate_xb<<<ablocks, 256, 0, stream>>>(xb2, als, ald, off, csr, aggb);
    gemm256_mfma<true><<<gblocks, 256, 0, stream>>>(aggb, W3, b3, nullptr,
                                                    batch, psum);

    pool_out<<<(GG + 3) / 4, 256, 0, stream>>>(psum, pcnt, lw, lb, out);
}

// Round 5
// 432.339 us; speedup vs baseline: 1.9207x; 1.9207x over previous
//
#include <hip/hip_runtime.h>
#include <hip/hip_bf16.h>

#define NN 100000
#define EE 800000
#define HH 4
#define CC 64
#define GG 2000
#define NB 98           // scan blocks: ceil((NN/4)/256)

typedef unsigned short ushortx;
typedef __attribute__((ext_vector_type(8))) short short8;
typedef __attribute__((ext_vector_type(4))) float f32x4;

// ---------------- CSR build ----------------

__global__ void hist_kernel(const int* __restrict__ ei, int* __restrict__ deg) {
    int e = blockIdx.x * 256 + threadIdx.x;
    const int tot = EE + NN;
    if (e < tot) {
        int d = (e < EE) ? ei[EE + e] : (e - EE);
        atomicAdd(&deg[d], 1);
    }
}

__global__ __launch_bounds__(256) void scan_blk(const int* __restrict__ deg,
                                                int* __restrict__ bsum) {
    const int t = threadIdx.x;
    const int idx4 = blockIdx.x * 256 + t;
    int4 v = {0, 0, 0, 0};
    if (idx4 < NN / 4) v = ((const int4*)deg)[idx4];
    int s = v.x + v.y + v.z + v.w;
#pragma unroll
    for (int m = 32; m; m >>= 1) s += __shfl_xor(s, m, 64);
    __shared__ int ws[4];
    if ((t & 63) == 0) ws[t >> 6] = s;
    __syncthreads();
    if (t == 0) bsum[blockIdx.x] = ws[0] + ws[1] + ws[2] + ws[3];
}

__global__ void scan_mid(const int* __restrict__ bsum, int* __restrict__ boff,
                         int* __restrict__ off) {
    __shared__ int sh[128];
    const int t = threadIdx.x;
    int v = (t < NB) ? bsum[t] : 0;
    sh[t] = v;
    __syncthreads();
    for (int d = 1; d < 128; d <<= 1) {
        int u = (t >= d) ? sh[t - d] : 0;
        __syncthreads();
        sh[t] += u;
        __syncthreads();
    }
    if (t < NB) boff[t] = sh[t] - v;
    if (t == NB - 1) off[NN] = sh[t];
}

__global__ __launch_bounds__(256) void scan_fin(const int* __restrict__ deg,
                                                const int* __restrict__ boff,
                                                int* __restrict__ off) {
    const int t = threadIdx.x;
    const int idx4 = blockIdx.x * 256 + t;
    int4 v = {0, 0, 0, 0};
    if (idx4 < NN / 4) v = ((const int4*)deg)[idx4];
    int s = v.x + v.y + v.z + v.w;
    const int lane = t & 63, w = t >> 6;
    int inc = s;
#pragma unroll
    for (int d = 1; d < 64; d <<= 1) {
        int u = __shfl_up(inc, d, 64);
        if (lane >= d) inc += u;
    }
    __shared__ int ws[4];
    if (lane == 63) ws[w] = inc;
    __syncthreads();
    int woff = 0;
    for (int i = 0; i < w; ++i) woff += ws[i];
    int excl = inc - s + woff + boff[blockIdx.x];
    if (idx4 < NN / 4) {
        int4 o;
        o.x = excl;
        o.y = o.x + v.x;
        o.z = o.y + v.y;
        o.w = o.z + v.z;
        ((int4*)off)[idx4] = o;
    }
}

__global__ void fill_kernel(const int* __restrict__ ei, const int* __restrict__ off,
                            int* __restrict__ cursor, int* __restrict__ csr_src) {
    int e = blockIdx.x * 256 + threadIdx.x;
    const int tot = EE + NN;
    if (e < tot) {
        int s, d;
        if (e < EE) { s = ei[e]; d = ei[EE + e]; }
        else        { s = e - EE; d = e - EE; }
        int p = off[d] + atomicAdd(&cursor[d], 1);
        csr_src[p] = s;
    }
}

__device__ __forceinline__ ushortx f2bf(float v) {
    __hip_bfloat16 b = __float2bfloat16(v);
    return *reinterpret_cast<ushortx*>(&b);
}

// ---------------- attention-vector precompute ----------------

__global__ void prep_va(const float* __restrict__ W, const float* __restrict__ as_,
                        const float* __restrict__ ad_, float* __restrict__ va,
                        int K) {
    int id = blockIdx.x * 256 + threadIdx.x;
    if (id >= K * 8) return;
    int k = id >> 3, comp = id & 7;
    int h = comp & 3, sd = comp >> 2;
    const float* a = sd ? ad_ : as_;
    const float* wrow = W + k * 256 + h * 64;
    const float* arow = a + h * 64;
    float s = 0.f;
    for (int c = 0; c < 64; ++c) s = fmaf(wrow[c], arow[c], s);
    va[k * 8 + comp] = s;
}

// W in MFMA fragment layout (bf16, pre-scaled by 1/4), computed ONCE:
// wfrag[((ct*8+kb)*64+lane)*8+j] = W[kw*256+h*64+c]*0.25 with c=ct*16+(lane&15),
// kap=kb*32+(lane>>4)*8+j, h=kap>>6, kw=kap&63. (Same mapping the R4 kernel
// staged per-block; now staged per-DEVICE.)
__global__ void prep_wfrag(const float* __restrict__ W, ushortx* __restrict__ wfrag) {
    int i = blockIdx.x * 256 + threadIdx.x;
    if (i >= 16384) return;
    int j = i & 7, lane = (i >> 3) & 63, kb = (i >> 9) & 7, ct = i >> 12;
    int c = ct * 16 + (lane & 15);
    int kap = kb * 32 + (lane >> 4) * 8 + j;
    int h = kap >> 6, kw = kap & 63;
    wfrag[i] = f2bf(W[kw * 256 + h * 64 + c] * 0.25f);
}

// ALS/ALD from fp32 X (layer 1, K=9).
template <int K>
__global__ __launch_bounds__(256) void att_gemv(
    const float* __restrict__ X, const float* __restrict__ va,
    float* __restrict__ ALS, float* __restrict__ ALD) {
    __shared__ float vs[K][8];
    const int tid = threadIdx.x;
    for (int i = tid; i < K * 8; i += 256) vs[i >> 3][i & 7] = va[i];
    __syncthreads();
    int n = blockIdx.x * 256 + tid;
    if (n >= NN) return;
    const float* xp = X + (size_t)n * K;
    float s0 = 0, s1 = 0, s2 = 0, s3 = 0, d0 = 0, d1 = 0, d2 = 0, d3 = 0;
#pragma unroll
    for (int k = 0; k < K; ++k) {
        float x1 = xp[k];
        const float4 vsv = *(const float4*)&vs[k][0];
        const float4 vdv = *(const float4*)&vs[k][4];
        s0 = fmaf(x1, vsv.x, s0); s1 = fmaf(x1, vsv.y, s1);
        s2 = fmaf(x1, vsv.z, s2); s3 = fmaf(x1, vsv.w, s3);
        d0 = fmaf(x1, vdv.x, d0); d1 = fmaf(x1, vdv.y, d1);
        d2 = fmaf(x1, vdv.z, d2); d3 = fmaf(x1, vdv.w, d3);
    }
    float4 so = {s0, s1, s2, s3}, dd = {d0, d1, d2, d3};
    ((float4*)ALS)[n] = so;
    ((float4*)ALD)[n] = dd;
}

// ALS/ALD from bf16 X (layers 2,3, K=64).
__global__ __launch_bounds__(256) void att_gemv_b(
    const ushortx* __restrict__ Xb, const float* __restrict__ va,
    float* __restrict__ ALS, float* __restrict__ ALD) {
    __shared__ float vs[64][8];
    const int tid = threadIdx.x;
    for (int i = tid; i < 64 * 8; i += 256) vs[i >> 3][i & 7] = va[i];
    __syncthreads();
    int n = blockIdx.x * 256 + tid;
    if (n >= NN) return;
    const uint4* xp = (const uint4*)(Xb + (size_t)n * 64);
    float s0 = 0, s1 = 0, s2 = 0, s3 = 0, d0 = 0, d1 = 0, d2 = 0, d3 = 0;
#pragma unroll
    for (int qq = 0; qq < 8; ++qq) {
        uint4 u = xp[qq];
        float xv[8];
        xv[0] = __uint_as_float(u.x << 16);
        xv[1] = __uint_as_float(u.x & 0xFFFF0000u);
        xv[2] = __uint_as_float(u.y << 16);
        xv[3] = __uint_as_float(u.y & 0xFFFF0000u);
        xv[4] = __uint_as_float(u.z << 16);
        xv[5] = __uint_as_float(u.z & 0xFFFF0000u);
        xv[6] = __uint_as_float(u.w << 16);
        xv[7] = __uint_as_float(u.w & 0xFFFF0000u);
#pragma unroll
        for (int j = 0; j < 8; ++j) {
            const int k = qq * 8 + j;
            const float4 vsv = *(const float4*)&vs[k][0];
            const float4 vdv = *(const float4*)&vs[k][4];
            s0 = fmaf(xv[j], vsv.x, s0); s1 = fmaf(xv[j], vsv.y, s1);
            s2 = fmaf(xv[j], vsv.z, s2); s3 = fmaf(xv[j], vsv.w, s3);
            d0 = fmaf(xv[j], vdv.x, d0); d1 = fmaf(xv[j], vdv.y, d1);
            d2 = fmaf(xv[j], vdv.z, d2); d3 = fmaf(xv[j], vdv.w, d3);
        }
    }
    float4 so = {s0, s1, s2, s3}, dd = {d0, d1, d2, d3};
    ((float4*)ALS)[n] = so;
    ((float4*)ALD)[n] = dd;
}

// ---------------- layer-1: aggregate raw x (K=9, fp32 exact) ---------------

__global__ __launch_bounds__(256) void aggregate_x1(
    const float* __restrict__ X, const float* __restrict__ ALS,
    const float* __restrict__ ALD, const int* __restrict__ off,
    const int* __restrict__ csr_src, float* __restrict__ AGG1) {
    __shared__ float2 wtab[4][4][66];      // [wave][head][edge(padded)]
    const int wv = threadIdx.x >> 6;
    const int node = blockIdx.x * 4 + wv;
    const int l = threadIdx.x & 63;
    if (node >= NN) return;
    const int beg = off[node], end = off[node + 1];
    const int h = l >> 4, kg = l & 15;
    const bool act = (kg < 9);
    const float4 aldv = ((const float4*)ALD)[node];
    const float2* wt2 = &wtab[wv][h][0];
    float acc = 0.f;
    float den = 0.f;

    for (int j0 = beg; j0 < end; j0 += 64) {
        const int cnt = min(64, end - j0);
        const int jj = j0 + l;
        int sv = 0;
        float4 w4 = {0.f, 0.f, 0.f, 0.f};
        if (jj < end) {
            sv = csr_src[jj];
            float4 a = ((const float4*)ALS)[sv];
            float vx = a.x + aldv.x, vy = a.y + aldv.y,
                  vz = a.z + aldv.z, vw = a.w + aldv.w;
            vx = (vx >= 0.f) ? vx : 0.2f * vx;
            vy = (vy >= 0.f) ? vy : 0.2f * vy;
            vz = (vz >= 0.f) ? vz : 0.2f * vz;
            vw = (vw >= 0.f) ? vw : 0.2f * vw;
            w4.x = __expf(vx); w4.y = __expf(vy);
            w4.z = __expf(vz); w4.w = __expf(vw);
        }
        const float fsv = __int_as_float(sv);
        wtab[wv][0][l] = make_float2(w4.x, fsv);
        wtab[wv][1][l] = make_float2(w4.y, fsv);
        wtab[wv][2][l] = make_float2(w4.z, fsv);
        wtab[wv][3][l] = make_float2(w4.w, fsv);
        __builtin_amdgcn_wave_barrier();
        asm volatile("s_waitcnt lgkmcnt(0)" ::: "memory");
        __builtin_amdgcn_sched_barrier(0);

        int t = 0;
        for (; t + 8 <= cnt; t += 8) {
            const float4 p01 = *(const float4*)&wt2[t];
            const float4 p23 = *(const float4*)&wt2[t + 2];
            const float4 p45 = *(const float4*)&wt2[t + 4];
            const float4 p67 = *(const float4*)&wt2[t + 6];
            float v0 = 0, v1 = 0, v2 = 0, v3 = 0, v4 = 0, v5 = 0, v6 = 0, v7 = 0;
            if (act) {
                v0 = X[(size_t)__float_as_int(p01.y) * 9 + kg];
                v1 = X[(size_t)__float_as_int(p01.w) * 9 + kg];
                v2 = X[(size_t)__float_as_int(p23.y) * 9 + kg];
                v3 = X[(size_t)__float_as_int(p23.w) * 9 + kg];
                v4 = X[(size_t)__float_as_int(p45.y) * 9 + kg];
                v5 = X[(size_t)__float_as_int(p45.w) * 9 + kg];
                v6 = X[(size_t)__float_as_int(p67.y) * 9 + kg];
                v7 = X[(size_t)__float_as_int(p67.w) * 9 + kg];
            }
            den += ((p01.x + p01.z) + (p23.x + p23.z)) +
                   ((p45.x + p45.z) + (p67.x + p67.z));
            acc = fmaf(p01.x, v0, acc); acc = fmaf(p01.z, v1, acc);
            acc = fmaf(p23.x, v2, acc); acc = fmaf(p23.z, v3, acc);
            acc = fmaf(p45.x, v4, acc); acc = fmaf(p45.z, v5, acc);
            acc = fmaf(p67.x, v6, acc); acc = fmaf(p67.z, v7, acc);
        }
        for (; t < cnt; t += 4) {
            const int t1 = min(t + 1, cnt - 1);
            const int t2 = min(t + 2, cnt - 1);
            const int t3 = min(t + 3, cnt - 1);
            float2 e0 = wt2[t], e1 = wt2[t1], e2 = wt2[t2], e3 = wt2[t3];
            float w0 = e0.x;
            float w1v = (t + 1 < cnt) ? e1.x : 0.f;
            float w2v = (t + 2 < cnt) ? e2.x : 0.f;
            float w3v = (t + 3 < cnt) ? e3.x : 0.f;
            float v0 = 0, v1 = 0, v2 = 0, v3 = 0;
            if (act) {
                v0 = X[(size_t)__float_as_int(e0.y) * 9 + kg];
                v1 = X[(size_t)__float_as_int(e1.y) * 9 + kg];
                v2 = X[(size_t)__float_as_int(e2.y) * 9 + kg];
                v3 = X[(size_t)__float_as_int(e3.y) * 9 + kg];
            }
            den += ((w0 + w1v) + (w2v + w3v));
            acc = fmaf(w0, v0, acc); acc = fmaf(w1v, v1, acc);
            acc = fmaf(w2v, v2, acc); acc = fmaf(w3v, v3, acc);
        }
        __builtin_amdgcn_wave_barrier();
    }

    const float inv = 1.f / (den + 1e-16f);
    AGG1[(size_t)node * 64 + l] = act ? acc * inv : 0.f;
}

// ---------------- layer-1 recovery GEMM: out = relu(1/4 AGG1.Wc + b) -------

__global__ __launch_bounds__(256) void gemm36(
    const float* __restrict__ AGG1, const float* __restrict__ W1,
    const float* __restrict__ b1, ushortx* __restrict__ Xb) {
    const int c = threadIdx.x & 63;
    const int wv = threadIdx.x >> 6;
    float wreg[36];
#pragma unroll
    for (int h = 0; h < 4; ++h)
#pragma unroll
        for (int k = 0; k < 9; ++k)
            wreg[h * 9 + k] = W1[k * 256 + h * 64 + c] * 0.25f;
    const float bc = b1[c];
    for (int row = blockIdx.x * 4 + wv; row < NN; row += gridDim.x * 4) {
        const float* xr = AGG1 + (size_t)row * 64;
        float s = 0.f;
#pragma unroll
        for (int h = 0; h < 4; ++h)
#pragma unroll
            for (int k = 0; k < 9; ++k)
                s = fmaf(wreg[h * 9 + k], xr[h * 16 + k], s);
        s = fmaxf(s + bc, 0.f);
        Xb[(size_t)row * 64 + c] = f2bf(s);
    }
}

// ---------------- layers 2,3: aggregate bf16 X (K=64) ----------------------

__global__ __launch_bounds__(256) void aggregate_xb(
    const ushortx* __restrict__ Xb, const float* __restrict__ ALS,
    const float* __restrict__ ALD, const int* __restrict__ off,
    const int* __restrict__ csr_src, ushortx* __restrict__ AGG) {
    __shared__ float2 wtab[4][4][66];      // [wave][head][edge(padded)]
    const int wv = threadIdx.x >> 6;
    const int node = blockIdx.x * 4 + wv;
    const int l = threadIdx.x & 63;
    if (node >= NN) return;
    const int beg = off[node], end = off[node + 1];
    const int h = l >> 4, kg = l & 15;
    const uint2* xb2 = (const uint2*)Xb;   // row = 16 uint2 (64 bf16)
    const float4 aldv = ((const float4*)ALD)[node];
    const float2* wt2 = &wtab[wv][h][0];
    float4 acc = {0.f, 0.f, 0.f, 0.f};
    float den = 0.f;

#define ACC4(uu, ww)                                                \
    {                                                               \
        float c0 = __uint_as_float((uu).x << 16);                   \
        float c1 = __uint_as_float((uu).x & 0xFFFF0000u);           \
        float c2 = __uint_as_float((uu).y << 16);                   \
        float c3 = __uint_as_float((uu).y & 0xFFFF0000u);           \
        acc.x = fmaf((ww), c0, acc.x);                              \
        acc.y = fmaf((ww), c1, acc.y);                              \
        acc.z = fmaf((ww), c2, acc.z);                              \
        acc.w = fmaf((ww), c3, acc.w);                              \
    }

    for (int j0 = beg; j0 < end; j0 += 64) {
        const int cnt = min(64, end - j0);
        const int jj = j0 + l;
        int sv = 0;
        float4 w4 = {0.f, 0.f, 0.f, 0.f};
        if (jj < end) {
            sv = csr_src[jj];
            float4 a = ((const float4*)ALS)[sv];
            float vx = a.x + aldv.x, vy = a.y + aldv.y,
                  vz = a.z + aldv.z, vw = a.w + aldv.w;
            vx = (vx >= 0.f) ? vx : 0.2f * vx;
            vy = (vy >= 0.f) ? vy : 0.2f * vy;
            vz = (vz >= 0.f) ? vz : 0.2f * vz;
            vw = (vw >= 0.f) ? vw : 0.2f * vw;
            w4.x = __expf(vx); w4.y = __expf(vy);
            w4.z = __expf(vz); w4.w = __expf(vw);
        }
        const float fsv = __int_as_float(sv);
        wtab[wv][0][l] = make_float2(w4.x, fsv);
        wtab[wv][1][l] = make_float2(w4.y, fsv);
        wtab[wv][2][l] = make_float2(w4.z, fsv);
        wtab[wv][3][l] = make_float2(w4.w, fsv);
        __builtin_amdgcn_wave_barrier();
        asm volatile("s_waitcnt lgkmcnt(0)" ::: "memory");
        __builtin_amdgcn_sched_barrier(0);

        int t = 0;
        for (; t + 8 <= cnt; t += 8) {
            const float4 p01 = *(const float4*)&wt2[t];
            const float4 p23 = *(const float4*)&wt2[t + 2];
            const float4 p45 = *(const float4*)&wt2[t + 4];
            const float4 p67 = *(const float4*)&wt2[t + 6];
            uint2 u0 = xb2[(size_t)__float_as_int(p01.y) * 16 + kg];
            uint2 u1 = xb2[(size_t)__float_as_int(p01.w) * 16 + kg];
            uint2 u2 = xb2[(size_t)__float_as_int(p23.y) * 16 + kg];
            uint2 u3 = xb2[(size_t)__float_as_int(p23.w) * 16 + kg];
            uint2 u4 = xb2[(size_t)__float_as_int(p45.y) * 16 + kg];
            uint2 u5 = xb2[(size_t)__float_as_int(p45.w) * 16 + kg];
            uint2 u6 = xb2[(size_t)__float_as_int(p67.y) * 16 + kg];
            uint2 u7 = xb2[(size_t)__float_as_int(p67.w) * 16 + kg];
            den += ((p01.x + p01.z) + (p23.x + p23.z)) +
                   ((p45.x + p45.z) + (p67.x + p67.z));
            ACC4(u0, p01.x);
            ACC4(u1, p01.z);
            ACC4(u2, p23.x);
            ACC4(u3, p23.z);
            ACC4(u4, p45.x);
            ACC4(u5, p45.z);
            ACC4(u6, p67.x);
            ACC4(u7, p67.z);
        }
        for (; t < cnt; t += 4) {
            const int t1 = min(t + 1, cnt - 1);
            const int t2 = min(t + 2, cnt - 1);
            const int t3 = min(t + 3, cnt - 1);
            float2 e0 = wt2[t], e1 = wt2[t1], e2 = wt2[t2], e3 = wt2[t3];
            float w0 = e0.x;
            float w1v = (t + 1 < cnt) ? e1.x : 0.f;
            float w2v = (t + 2 < cnt) ? e2.x : 0.f;
            float w3v = (t + 3 < cnt) ? e3.x : 0.f;
            uint2 u0 = xb2[(size_t)__float_as_int(e0.y) * 16 + kg];
            uint2 u1 = xb2[(size_t)__float_as_int(e1.y) * 16 + kg];
            uint2 u2 = xb2[(size_t)__float_as_int(e2.y) * 16 + kg];
            uint2 u3 = xb2[(size_t)__float_as_int(e3.y) * 16 + kg];
            den += ((w0 + w1v) + (w2v + w3v));
            ACC4(u0, w0);
            ACC4(u1, w1v);
            ACC4(u2, w2v);
            ACC4(u3, w3v);
        }
        __builtin_amdgcn_wave_barrier();
    }
#undef ACC4

    const float inv = 1.f / (den + 1e-16f);
    uint p0 = (uint)f2bf(acc.x * inv) | ((uint)f2bf(acc.y * inv) << 16);
    uint p1 = (uint)f2bf(acc.z * inv) | ((uint)f2bf(acc.w * inv) << 16);
    uint2 ov = {p0, p1};
    *(uint2*)&AGG[(size_t)node * 256 + (size_t)l * 4] = ov;
}

// ---------------- recovery GEMM (K=256) on matrix cores --------------------
// out[n,c] = relu(sum_{h,k} AGG[n,h*64+k] * W[k,h*64+c]/4 + b[c]).
// W fragments pre-staged by prep_wfrag; block staging = 8 coalesced
// uint4->ds_write_b128 copies (conflict-free). Grid 512 -> ~3 tile iters per
// staging. F32OUT=false: bf16 X for next layer. F32OUT=true: fp32 rows for
// pool_graph (keeps pooling precision; NO atomics).

template <bool F32OUT>
__global__ __launch_bounds__(256) void gemm256_mfma(
    const ushortx* __restrict__ AGG, const ushortx* __restrict__ wfrag,
    const float* __restrict__ bias, ushortx* __restrict__ Xb,
    float* __restrict__ OUTF) {
    __shared__ ushortx wt[4][8][64][8];    // [ct][kb][lane][j]  (32 KB)
    const int tid = threadIdx.x;
    const int l = tid & 63, wv = tid >> 6;
    const int n = l & 15, q = l >> 4;

    {
        const uint4* src = (const uint4*)wfrag;
        uint4* dst = (uint4*)&wt[0][0][0][0];
#pragma unroll
        for (int i = 0; i < 8; ++i) dst[i * 256 + tid] = src[i * 256 + tid];
    }
    __syncthreads();

    for (int row0 = blockIdx.x * 64 + wv * 16; row0 < NN; row0 += gridDim.x * 64) {
        f32x4 acc[4] = {{0.f, 0.f, 0.f, 0.f}, {0.f, 0.f, 0.f, 0.f},
                        {0.f, 0.f, 0.f, 0.f}, {0.f, 0.f, 0.f, 0.f}};
#pragma unroll
        for (int kb = 0; kb < 8; ++kb) {
            short8 a = *(const short8*)&AGG[(size_t)(row0 + n) * 256 + kb * 32 + q * 8];
#pragma unroll
            for (int ct = 0; ct < 4; ++ct) {
                short8 b = *(const short8*)&wt[ct][kb][l][0];
                acc[ct] = __builtin_amdgcn_mfma_f32_16x16x32_bf16(b, a, acc[ct], 0, 0, 0);
            }
        }
        const int row = row0 + n;
#pragma unroll
        for (int ct = 0; ct < 4; ++ct) {
            const int col = ct * 16 + q * 4;
            float4 b4 = ((const float4*)bias)[ct * 4 + q];
            float o0 = fmaxf(acc[ct][0] + b4.x, 0.f);
            float o1 = fmaxf(acc[ct][1] + b4.y, 0.f);
            float o2 = fmaxf(acc[ct][2] + b4.z, 0.f);
            float o3 = fmaxf(acc[ct][3] + b4.w, 0.f);
            if constexpr (F32OUT) {
                float4 ov = {o0, o1, o2, o3};
                *(float4*)&OUTF[(size_t)row * 64 + col] = ov;
            } else {
                uint p0 = (uint)f2bf(o0) | ((uint)f2bf(o1) << 16);
                uint p1 = (uint)f2bf(o2) | ((uint)f2bf(o3) << 16);
                uint2 ov = {p0, p1};
                *(uint2*)&Xb[(size_t)row * 64 + col] = ov;
            }
        }
    }
}

// ---------------- graph mean-pool + final linear (no atomics) --------------
// One wave per graph: binary-search node range in sorted batch, sum fp32
// node outputs, dot with lin_w, butterfly, write out[g].

__global__ __launch_bounds__(256) void pool_graph(
    const float* __restrict__ OUTF, const int* __restrict__ batch,
    const float* __restrict__ lw, const float* __restrict__ lb,
    float* __restrict__ out) {
    const int g = blockIdx.x * 4 + (threadIdx.x >> 6);
    const int l = threadIdx.x & 63;
    if (g >= GG) return;
    int lo = 0, hi = NN;
    while (lo < hi) { int mid = (lo + hi) >> 1; if (batch[mid] < g) lo = mid + 1; else hi = mid; }
    int lo2 = lo, hi2 = NN;
    while (lo2 < hi2) { int mid = (lo2 + hi2) >> 1; if (batch[mid] < g + 1) lo2 = mid + 1; else hi2 = mid; }
    float s = 0.f;
    int nn = lo;
    for (; nn + 4 <= lo2; nn += 4) {
        float a0 = OUTF[(size_t)(nn + 0) * 64 + l];
        float a1 = OUTF[(size_t)(nn + 1) * 64 + l];
        float a2 = OUTF[(size_t)(nn + 2) * 64 + l];
        float a3 = OUTF[(size_t)(nn + 3) * 64 + l];
        s += (a0 + a1) + (a2 + a3);
    }
    for (; nn < lo2; ++nn) s += OUTF[(size_t)nn * 64 + l];
    const float cntf = fmaxf((float)(lo2 - lo), 1.f);
    float v = s / cntf * lw[l];
#pragma unroll
    for (int m = 32; m; m >>= 1) v += __shfl_xor(v, m, 64);
    if (l == 0) out[g] = v + lb[0];
}

// ---------------- launch ----------------

extern "C" void kernel_launch(void* const* d_in, const int* in_sizes, int n_in,
                              void* d_out, int out_size, void* d_ws, size_t ws_size,
                              hipStream_t stream) {
    const float* x     = (const float*)d_in[0];
    const int*   ei    = (const int*)d_in[1];
    const int*   batch = (const int*)d_in[2];
    const float* W1  = (const float*)d_in[3];
    const float* as1 = (const float*)d_in[4];
    const float* ad1 = (const float*)d_in[5];
    const float* b1  = (const float*)d_in[6];
    const float* W2  = (const float*)d_in[7];
    const float* as2 = (const float*)d_in[8];
    const float* ad2 = (const float*)d_in[9];
    const float* b2  = (const float*)d_in[10];
    const float* W3  = (const float*)d_in[11];
    const float* as3 = (const float*)d_in[12];
    const float* ad3 = (const float*)d_in[13];
    const float* b3  = (const float*)d_in[14];
    const float* lw  = (const float*)d_in[15];
    const float* lb  = (const float*)d_in[16];
    float* out = (float*)d_out;

    char* p = (char*)d_ws;
    auto carve = [&](size_t bytes) -> void* {
        void* r = (void*)p;
        p += (bytes + 255) & ~(size_t)255;
        return r;
    };
    int*     off    = (int*)carve((NN + 4) * sizeof(int));
    int*     deg    = (int*)carve(NN * sizeof(int));
    int*     cursor = (int*)carve(NN * sizeof(int));
    int*     bsum   = (int*)carve(NB * sizeof(int));
    int*     boff   = (int*)carve(NB * sizeof(int));
    int*     csr    = (int*)carve((size_t)(EE + NN) * sizeof(int));
    ushortx* aggb   = (ushortx*)carve((size_t)NN * 256 * sizeof(ushortx));  // 51.2 MB
    float*   agg1   = (float*)carve((size_t)NN * 64 * sizeof(float));       // 25.6 MB
    ushortx* xb1    = (ushortx*)carve((size_t)NN * 64 * sizeof(ushortx));   // 12.8 MB
    float*   outf   = (float*)carve((size_t)NN * 64 * sizeof(float));       // 25.6 MB
    float*   als    = (float*)carve((size_t)NN * 4 * sizeof(float));
    float*   ald    = (float*)carve((size_t)NN * 4 * sizeof(float));
    float*   va1    = (float*)carve(9 * 8 * sizeof(float));
    float*   va2    = (float*)carve(64 * 8 * sizeof(float));
    float*   va3    = (float*)carve(64 * 8 * sizeof(float));
    ushortx* wf2    = (ushortx*)carve(16384 * sizeof(ushortx));
    ushortx* wf3    = (ushortx*)carve(16384 * sizeof(ushortx));
    // xb2 aliases agg1 (agg1 dead after gemm36; xb2 first written by L2 GEMM)
    ushortx* xb2 = (ushortx*)agg1;

    hipMemsetAsync(deg, 0, NN * sizeof(int), stream);
    hipMemsetAsync(cursor, 0, NN * sizeof(int), stream);

    const int etot = EE + NN;
    const int eblocks = (etot + 255) / 256;
    hist_kernel<<<eblocks, 256, 0, stream>>>(ei, deg);
    scan_blk<<<NB, 256, 0, stream>>>(deg, bsum);
    scan_mid<<<1, 128, 0, stream>>>(bsum, boff, off);
    scan_fin<<<NB, 256, 0, stream>>>(deg, boff, off);
    fill_kernel<<<eblocks, 256, 0, stream>>>(ei, off, cursor, csr);

    prep_va<<<1, 256, 0, stream>>>(W1, as1, ad1, va1, 9);
    prep_va<<<2, 256, 0, stream>>>(W2, as2, ad2, va2, 64);
    prep_va<<<2, 256, 0, stream>>>(W3, as3, ad3, va3, 64);
    prep_wfrag<<<64, 256, 0, stream>>>(W2, wf2);
    prep_wfrag<<<64, 256, 0, stream>>>(W3, wf3);

    const int ablocks = (NN + 3) / 4;
    const int nblocks = (NN + 255) / 256;

    // layer 1 (fp32 exact: aggregate x, then K=36 GEMM)
    att_gemv<9><<<nblocks, 256, 0, stream>>>(x, va1, als, ald);
    aggregate_x1<<<ablocks, 256, 0, stream>>>(x, als, ald, off, csr, agg1);
    gemm36<<<2048, 256, 0, stream>>>(agg1, W1, b1, xb1);

    // layer 2
    att_gemv_b<<<nblocks, 256, 0, stream>>>(xb1, va2, als, ald);
    aggregate_xb<<<ablocks, 256, 0, stream>>>(xb1, als, ald, off, csr, aggb);
    gemm256_mfma<false><<<512, 256, 0, stream>>>(aggb, wf2, b2, xb2, nullptr);

    // layer 3 (fp32 node outputs; pooling in dedicated kernel, no atomics)
    att_gemv_b<<<nblocks, 256, 0, stream>>>(xb2, va3, als, ald);
    aggregate_xb<<<ablocks, 256, 0, stream>>>(xb2, als, ald, off, csr, aggb);
    gemm256_mfma<true><<<512, 256, 0, stream>>>(aggb, wf3, b3, nullptr, outf);

    pool_graph<<<(GG + 3) / 4, 256, 0, stream>>>(outf, batch, lw, lb, out);
}

// Round 7
// 384.332 us; speedup vs baseline: 2.1606x; 1.1249x over previous
//
#include <hip/hip_runtime.h>
#include <hip/hip_bf16.h>

#define NN 100000
#define EE 800000
#define HH 4
#define CC 64
#define GG 2000
#define NB 98           // scan blocks: ceil((NN/4)/256)

typedef unsigned short ushortx;
typedef __attribute__((ext_vector_type(8))) short short8;
typedef __attribute__((ext_vector_type(4))) float f32x4;

// ---------------- CSR build ----------------
// hist: atomicAdd's RETURN is the edge's within-dst rank -- store it
// (coalesced). fill then needs NO atomic: p = off[d] + rank[e].

__global__ void hist_kernel(const int* __restrict__ ei, int* __restrict__ deg,
                            int* __restrict__ rank) {
    int e = blockIdx.x * 256 + threadIdx.x;
    const int tot = EE + NN;
    if (e < tot) {
        int d = (e < EE) ? ei[EE + e] : (e - EE);
        rank[e] = atomicAdd(&deg[d], 1);
    }
}

__global__ __launch_bounds__(256) void scan_blk(const int* __restrict__ deg,
                                                int* __restrict__ bsum) {
    const int t = threadIdx.x;
    const int idx4 = blockIdx.x * 256 + t;
    int4 v = {0, 0, 0, 0};
    if (idx4 < NN / 4) v = ((const int4*)deg)[idx4];
    int s = v.x + v.y + v.z + v.w;
#pragma unroll
    for (int m = 32; m; m >>= 1) s += __shfl_xor(s, m, 64);
    __shared__ int ws[4];
    if ((t & 63) == 0) ws[t >> 6] = s;
    __syncthreads();
    if (t == 0) bsum[blockIdx.x] = ws[0] + ws[1] + ws[2] + ws[3];
}

__global__ void scan_mid(const int* __restrict__ bsum, int* __restrict__ boff,
                         int* __restrict__ off) {
    __shared__ int sh[128];
    const int t = threadIdx.x;
    int v = (t < NB) ? bsum[t] : 0;
    sh[t] = v;
    __syncthreads();
    for (int d = 1; d < 128; d <<= 1) {
        int u = (t >= d) ? sh[t - d] : 0;
        __syncthreads();
        sh[t] += u;
        __syncthreads();
    }
    if (t < NB) boff[t] = sh[t] - v;
    if (t == NB - 1) off[NN] = sh[t];
}

__global__ __launch_bounds__(256) void scan_fin(const int* __restrict__ deg,
                                                const int* __restrict__ boff,
                                                int* __restrict__ off) {
    const int t = threadIdx.x;
    const int idx4 = blockIdx.x * 256 + t;
    int4 v = {0, 0, 0, 0};
    if (idx4 < NN / 4) v = ((const int4*)deg)[idx4];
    int s = v.x + v.y + v.z + v.w;
    const int lane = t & 63, w = t >> 6;
    int inc = s;
#pragma unroll
    for (int d = 1; d < 64; d <<= 1) {
        int u = __shfl_up(inc, d, 64);
        if (lane >= d) inc += u;
    }
    __shared__ int ws[4];
    if (lane == 63) ws[w] = inc;
    __syncthreads();
    int woff = 0;
    for (int i = 0; i < w; ++i) woff += ws[i];
    int excl = inc - s + woff + boff[blockIdx.x];
    if (idx4 < NN / 4) {
        int4 o;
        o.x = excl;
        o.y = o.x + v.x;
        o.z = o.y + v.y;
        o.w = o.z + v.z;
        ((int4*)off)[idx4] = o;
    }
}

// XCD-sharded fill: shard = blockIdx&7 (matches round-robin block->XCD),
// each shard filters the full edge stream to its contiguous 12.5k-node dst
// range. off monotonic -> shard writes a CONTIGUOUS ~450KB csr slice ->
// lines accumulate in one XCD's L2 and write back full. No atomics.
__global__ __launch_bounds__(256) void fill_sharded(
    const int* __restrict__ ei, const int* __restrict__ off,
    const int* __restrict__ rank, int* __restrict__ csr_src) {
    const int shard = blockIdx.x & 7;
    const int wblk = blockIdx.x >> 3;       // 0..255 within shard
    const int lo = shard * (NN / 8);
    const int hi = lo + (NN / 8);
    const int tot = EE + NN;
    for (int e = wblk * 256 + threadIdx.x; e < tot; e += 256 * 256) {
        int d = (e < EE) ? ei[EE + e] : (e - EE);
        if (d >= lo && d < hi) {
            int s = (e < EE) ? ei[e] : (e - EE);
            csr_src[off[d] + rank[e]] = s;
        }
    }
}

__device__ __forceinline__ ushortx f2bf(float v) {
    __hip_bfloat16 b = __float2bfloat16(v);
    return *reinterpret_cast<ushortx*>(&b);
}

// ---------------- parameter precompute (single merged kernel) ---------------

__device__ __forceinline__ void do_va(const float* __restrict__ W,
                                      const float* __restrict__ as_,
                                      const float* __restrict__ ad_,
                                      float* __restrict__ va, int K, int id) {
    if (id >= K * 8) return;
    int k = id >> 3, comp = id & 7;
    int h = comp & 3, sd = comp >> 2;
    const float* a = sd ? ad_ : as_;
    const float* wrow = W + k * 256 + h * 64;
    const float* arow = a + h * 64;
    float s = 0.f;
    for (int c = 0; c < 64; ++c) s = fmaf(wrow[c], arow[c], s);
    va[k * 8 + comp] = s;
}

// W in MFMA fragment layout (bf16, pre-scaled by 1/4):
// wfrag[((ct*8+kb)*64+lane)*8+j] = W[kw*256+h*64+c]*0.25, c=ct*16+(lane&15),
// kap=kb*32+(lane>>4)*8+j, h=kap>>6, kw=kap&63.
__device__ __forceinline__ void do_wfrag(const float* __restrict__ W,
                                         ushortx* __restrict__ wfrag, int i) {
    if (i >= 16384) return;
    int j = i & 7, lane = (i >> 3) & 63, kb = (i >> 9) & 7, ct = i >> 12;
    int c = ct * 16 + (lane & 15);
    int kap = kb * 32 + (lane >> 4) * 8 + j;
    int h = kap >> 6, kw = kap & 63;
    wfrag[i] = f2bf(W[kw * 256 + h * 64 + c] * 0.25f);
}

__global__ void prep_all(
    const float* __restrict__ W1, const float* __restrict__ as1,
    const float* __restrict__ ad1, const float* __restrict__ W2,
    const float* __restrict__ as2, const float* __restrict__ ad2,
    const float* __restrict__ W3, const float* __restrict__ as3,
    const float* __restrict__ ad3, float* __restrict__ va1,
    float* __restrict__ va2, float* __restrict__ va3,
    ushortx* __restrict__ wf2, ushortx* __restrict__ wf3) {
    const int b = blockIdx.x, tid = threadIdx.x;
    if (b == 0) do_va(W1, as1, ad1, va1, 9, tid);
    else if (b <= 2) do_va(W2, as2, ad2, va2, 64, (b - 1) * 256 + tid);
    else if (b <= 4) do_va(W3, as3, ad3, va3, 64, (b - 3) * 256 + tid);
    else if (b <= 68) do_wfrag(W2, wf2, (b - 5) * 256 + tid);
    else do_wfrag(W3, wf3, (b - 69) * 256 + tid);
}

// ALS/ALD from fp32 X (layer 1, K=9).
template <int K>
__global__ __launch_bounds__(256) void att_gemv(
    const float* __restrict__ X, const float* __restrict__ va,
    float* __restrict__ ALS, float* __restrict__ ALD) {
    __shared__ float vs[K][8];
    const int tid = threadIdx.x;
    for (int i = tid; i < K * 8; i += 256) vs[i >> 3][i & 7] = va[i];
    __syncthreads();
    int n = blockIdx.x * 256 + tid;
    if (n >= NN) return;
    const float* xp = X + (size_t)n * K;
    float s0 = 0, s1 = 0, s2 = 0, s3 = 0, d0 = 0, d1 = 0, d2 = 0, d3 = 0;
#pragma unroll
    for (int k = 0; k < K; ++k) {
        float x1 = xp[k];
        const float4 vsv = *(const float4*)&vs[k][0];
        const float4 vdv = *(const float4*)&vs[k][4];
        s0 = fmaf(x1, vsv.x, s0); s1 = fmaf(x1, vsv.y, s1);
        s2 = fmaf(x1, vsv.z, s2); s3 = fmaf(x1, vsv.w, s3);
        d0 = fmaf(x1, vdv.x, d0); d1 = fmaf(x1, vdv.y, d1);
        d2 = fmaf(x1, vdv.z, d2); d3 = fmaf(x1, vdv.w, d3);
    }
    float4 so = {s0, s1, s2, s3}, dd = {d0, d1, d2, d3};
    ((float4*)ALS)[n] = so;
    ((float4*)ALD)[n] = dd;
}

// ALS/ALD from bf16 X (layers 2,3, K=64).
__global__ __launch_bounds__(256) void att_gemv_b(
    const ushortx* __restrict__ Xb, const float* __restrict__ va,
    float* __restrict__ ALS, float* __restrict__ ALD) {
    __shared__ float vs[64][8];
    const int tid = threadIdx.x;
    for (int i = tid; i < 64 * 8; i += 256) vs[i >> 3][i & 7] = va[i];
    __syncthreads();
    int n = blockIdx.x * 256 + tid;
    if (n >= NN) return;
    const uint4* xp = (const uint4*)(Xb + (size_t)n * 64);
    float s0 = 0, s1 = 0, s2 = 0, s3 = 0, d0 = 0, d1 = 0, d2 = 0, d3 = 0;
#pragma unroll
    for (int qq = 0; qq < 8; ++qq) {
        uint4 u = xp[qq];
        float xv[8];
        xv[0] = __uint_as_float(u.x << 16);
        xv[1] = __uint_as_float(u.x & 0xFFFF0000u);
        xv[2] = __uint_as_float(u.y << 16);
        xv[3] = __uint_as_float(u.y & 0xFFFF0000u);
        xv[4] = __uint_as_float(u.z << 16);
        xv[5] = __uint_as_float(u.z & 0xFFFF0000u);
        xv[6] = __uint_as_float(u.w << 16);
        xv[7] = __uint_as_float(u.w & 0xFFFF0000u);
#pragma unroll
        for (int j = 0; j < 8; ++j) {
            const int k = qq * 8 + j;
            const float4 vsv = *(const float4*)&vs[k][0];
            const float4 vdv = *(const float4*)&vs[k][4];
            s0 = fmaf(xv[j], vsv.x, s0); s1 = fmaf(xv[j], vsv.y, s1);
            s2 = fmaf(xv[j], vsv.z, s2); s3 = fmaf(xv[j], vsv.w, s3);
            d0 = fmaf(xv[j], vdv.x, d0); d1 = fmaf(xv[j], vdv.y, d1);
            d2 = fmaf(xv[j], vdv.z, d2); d3 = fmaf(xv[j], vdv.w, d3);
        }
    }
    float4 so = {s0, s1, s2, s3}, dd = {d0, d1, d2, d3};
    ((float4*)ALS)[n] = so;
    ((float4*)ALD)[n] = dd;
}

// ---------------- layer-1: aggregate raw x (K=9, fp32 exact) ---------------

__global__ __launch_bounds__(256) void aggregate_x1(
    const float* __restrict__ X, const float* __restrict__ ALS,
    const float* __restrict__ ALD, const int* __restrict__ off,
    const int* __restrict__ csr_src, float* __restrict__ AGG1) {
    __shared__ float2 wtab[4][4][66];      // [wave][head][edge(padded)]
    const int wv = threadIdx.x >> 6;
    const int node = blockIdx.x * 4 + wv;
    const int l = threadIdx.x & 63;
    if (node >= NN) return;
    const int beg = off[node], end = off[node + 1];
    const int h = l >> 4, kg = l & 15;
    const bool act = (kg < 9);
    const float4 aldv = ((const float4*)ALD)[node];
    const float2* wt2 = &wtab[wv][h][0];
    float acc = 0.f;
    float den = 0.f;

    for (int j0 = beg; j0 < end; j0 += 64) {
        const int cnt = min(64, end - j0);
        const int jj = j0 + l;
        int sv = 0;
        float4 w4 = {0.f, 0.f, 0.f, 0.f};
        if (jj < end) {
            sv = csr_src[jj];
            float4 a = ((const float4*)ALS)[sv];
            float vx = a.x + aldv.x, vy = a.y + aldv.y,
                  vz = a.z + aldv.z, vw = a.w + aldv.w;
            vx = (vx >= 0.f) ? vx : 0.2f * vx;
            vy = (vy >= 0.f) ? vy : 0.2f * vy;
            vz = (vz >= 0.f) ? vz : 0.2f * vz;
            vw = (vw >= 0.f) ? vw : 0.2f * vw;
            w4.x = __expf(vx); w4.y = __expf(vy);
            w4.z = __expf(vz); w4.w = __expf(vw);
        }
        const float fsv = __int_as_float(sv);
        wtab[wv][0][l] = make_float2(w4.x, fsv);
        wtab[wv][1][l] = make_float2(w4.y, fsv);
        wtab[wv][2][l] = make_float2(w4.z, fsv);
        wtab[wv][3][l] = make_float2(w4.w, fsv);
        __builtin_amdgcn_wave_barrier();
        asm volatile("s_waitcnt lgkmcnt(0)" ::: "memory");
        __builtin_amdgcn_sched_barrier(0);

        int t = 0;
        for (; t + 8 <= cnt; t += 8) {
            const float4 p01 = *(const float4*)&wt2[t];
            const float4 p23 = *(const float4*)&wt2[t + 2];
            const float4 p45 = *(const float4*)&wt2[t + 4];
            const float4 p67 = *(const float4*)&wt2[t + 6];
            float v0 = 0, v1 = 0, v2 = 0, v3 = 0, v4 = 0, v5 = 0, v6 = 0, v7 = 0;
            if (act) {
                v0 = X[(size_t)__float_as_int(p01.y) * 9 + kg];
                v1 = X[(size_t)__float_as_int(p01.w) * 9 + kg];
                v2 = X[(size_t)__float_as_int(p23.y) * 9 + kg];
                v3 = X[(size_t)__float_as_int(p23.w) * 9 + kg];
                v4 = X[(size_t)__float_as_int(p45.y) * 9 + kg];
                v5 = X[(size_t)__float_as_int(p45.w) * 9 + kg];
                v6 = X[(size_t)__float_as_int(p67.y) * 9 + kg];
                v7 = X[(size_t)__float_as_int(p67.w) * 9 + kg];
            }
            den += ((p01.x + p01.z) + (p23.x + p23.z)) +
                   ((p45.x + p45.z) + (p67.x + p67.z));
            acc = fmaf(p01.x, v0, acc); acc = fmaf(p01.z, v1, acc);
            acc = fmaf(p23.x, v2, acc); acc = fmaf(p23.z, v3, acc);
            acc = fmaf(p45.x, v4, acc); acc = fmaf(p45.z, v5, acc);
            acc = fmaf(p67.x, v6, acc); acc = fmaf(p67.z, v7, acc);
        }
        for (; t < cnt; t += 4) {
            const int t1 = min(t + 1, cnt - 1);
            const int t2 = min(t + 2, cnt - 1);
            const int t3 = min(t + 3, cnt - 1);
            float2 e0 = wt2[t], e1 = wt2[t1], e2 = wt2[t2], e3 = wt2[t3];
            float w0 = e0.x;
            float w1v = (t + 1 < cnt) ? e1.x : 0.f;
            float w2v = (t + 2 < cnt) ? e2.x : 0.f;
            float w3v = (t + 3 < cnt) ? e3.x : 0.f;
            float v0 = 0, v1 = 0, v2 = 0, v3 = 0;
            if (act) {
                v0 = X[(size_t)__float_as_int(e0.y) * 9 + kg];
                v1 = X[(size_t)__float_as_int(e1.y) * 9 + kg];
                v2 = X[(size_t)__float_as_int(e2.y) * 9 + kg];
                v3 = X[(size_t)__float_as_int(e3.y) * 9 + kg];
            }
            den += ((w0 + w1v) + (w2v + w3v));
            acc = fmaf(w0, v0, acc); acc = fmaf(w1v, v1, acc);
            acc = fmaf(w2v, v2, acc); acc = fmaf(w3v, v3, acc);
        }
        __builtin_amdgcn_wave_barrier();
    }

    const float inv = 1.f / (den + 1e-16f);
    AGG1[(size_t)node * 64 + l] = act ? acc * inv : 0.f;
}

// ---------------- layer-1 recovery GEMM: out = relu(1/4 AGG1.Wc + b) -------

__global__ __launch_bounds__(256) void gemm36(
    const float* __restrict__ AGG1, const float* __restrict__ W1,
    const float* __restrict__ b1, ushortx* __restrict__ Xb) {
    const int c = threadIdx.x & 63;
    const int wv = threadIdx.x >> 6;
    float wreg[36];
#pragma unroll
    for (int h = 0; h < 4; ++h)
#pragma unroll
        for (int k = 0; k < 9; ++k)
            wreg[h * 9 + k] = W1[k * 256 + h * 64 + c] * 0.25f;
    const float bc = b1[c];
    for (int row = blockIdx.x * 4 + wv; row < NN; row += gridDim.x * 4) {
        const float* xr = AGG1 + (size_t)row * 64;
        float s = 0.f;
#pragma unroll
        for (int h = 0; h < 4; ++h)
#pragma unroll
            for (int k = 0; k < 9; ++k)
                s = fmaf(wreg[h * 9 + k], xr[h * 16 + k], s);
        s = fmaxf(s + bc, 0.f);
        Xb[(size_t)row * 64 + c] = f2bf(s);
    }
}

// ---------------- layers 2,3: aggregate bf16 X (K=64) ----------------------

__global__ __launch_bounds__(256) void aggregate_xb(
    const ushortx* __restrict__ Xb, const float* __restrict__ ALS,
    const float* __restrict__ ALD, const int* __restrict__ off,
    const int* __restrict__ csr_src, ushortx* __restrict__ AGG) {
    __shared__ float2 wtab[4][4][66];      // [wave][head][edge(padded)]
    const int wv = threadIdx.x >> 6;
    const int node = blockIdx.x * 4 + wv;
    const int l = threadIdx.x & 63;
    if (node >= NN) return;
    const int beg = off[node], end = off[node + 1];
    const int h = l >> 4, kg = l & 15;
    const uint2* xb2 = (const uint2*)Xb;   // row = 16 uint2 (64 bf16)
    const float4 aldv = ((const float4*)ALD)[node];
    const float2* wt2 = &wtab[wv][h][0];
    float4 acc = {0.f, 0.f, 0.f, 0.f};
    float den = 0.f;

#define ACC4(uu, ww)                                                \
    {                                                               \
        float c0 = __uint_as_float((uu).x << 16);                   \
        float c1 = __uint_as_float((uu).x & 0xFFFF0000u);           \
        float c2 = __uint_as_float((uu).y << 16);                   \
        float c3 = __uint_as_float((uu).y & 0xFFFF0000u);           \
        acc.x = fmaf((ww), c0, acc.x);                              \
        acc.y = fmaf((ww), c1, acc.y);                              \
        acc.z = fmaf((ww), c2, acc.z);                              \
        acc.w = fmaf((ww), c3, acc.w);                              \
    }

    for (int j0 = beg; j0 < end; j0 += 64) {
        const int cnt = min(64, end - j0);
        const int jj = j0 + l;
        int sv = 0;
        float4 w4 = {0.f, 0.f, 0.f, 0.f};
        if (jj < end) {
            sv = csr_src[jj];
            float4 a = ((const float4*)ALS)[sv];
            float vx = a.x + aldv.x, vy = a.y + aldv.y,
                  vz = a.z + aldv.z, vw = a.w + aldv.w;
            vx = (vx >= 0.f) ? vx : 0.2f * vx;
            vy = (vy >= 0.f) ? vy : 0.2f * vy;
            vz = (vz >= 0.f) ? vz : 0.2f * vz;
            vw = (vw >= 0.f) ? vw : 0.2f * vw;
            w4.x = __expf(vx); w4.y = __expf(vy);
            w4.z = __expf(vz); w4.w = __expf(vw);
        }
        const float fsv = __int_as_float(sv);
        wtab[wv][0][l] = make_float2(w4.x, fsv);
        wtab[wv][1][l] = make_float2(w4.y, fsv);
        wtab[wv][2][l] = make_float2(w4.z, fsv);
        wtab[wv][3][l] = make_float2(w4.w, fsv);
        __builtin_amdgcn_wave_barrier();
        asm volatile("s_waitcnt lgkmcnt(0)" ::: "memory");
        __builtin_amdgcn_sched_barrier(0);

        int t = 0;
        for (; t + 8 <= cnt; t += 8) {
            const float4 p01 = *(const float4*)&wt2[t];
            const float4 p23 = *(const float4*)&wt2[t + 2];
            const float4 p45 = *(const float4*)&wt2[t + 4];
            const float4 p67 = *(const float4*)&wt2[t + 6];
            uint2 u0 = xb2[(size_t)__float_as_int(p01.y) * 16 + kg];
            uint2 u1 = xb2[(size_t)__float_as_int(p01.w) * 16 + kg];
            uint2 u2 = xb2[(size_t)__float_as_int(p23.y) * 16 + kg];
            uint2 u3 = xb2[(size_t)__float_as_int(p23.w) * 16 + kg];
            uint2 u4 = xb2[(size_t)__float_as_int(p45.y) * 16 + kg];
            uint2 u5 = xb2[(size_t)__float_as_int(p45.w) * 16 + kg];
            uint2 u6 = xb2[(size_t)__float_as_int(p67.y) * 16 + kg];
            uint2 u7 = xb2[(size_t)__float_as_int(p67.w) * 16 + kg];
            den += ((p01.x + p01.z) + (p23.x + p23.z)) +
                   ((p45.x + p45.z) + (p67.x + p67.z));
            ACC4(u0, p01.x);
            ACC4(u1, p01.z);
            ACC4(u2, p23.x);
            ACC4(u3, p23.z);
            ACC4(u4, p45.x);
            ACC4(u5, p45.z);
            ACC4(u6, p67.x);
            ACC4(u7, p67.z);
        }
        for (; t < cnt; t += 4) {
            const int t1 = min(t + 1, cnt - 1);
            const int t2 = min(t + 2, cnt - 1);
            const int t3 = min(t + 3, cnt - 1);
            float2 e0 = wt2[t], e1 = wt2[t1], e2 = wt2[t2], e3 = wt2[t3];
            float w0 = e0.x;
            float w1v = (t + 1 < cnt) ? e1.x : 0.f;
            float w2v = (t + 2 < cnt) ? e2.x : 0.f;
            float w3v = (t + 3 < cnt) ? e3.x : 0.f;
            uint2 u0 = xb2[(size_t)__float_as_int(e0.y) * 16 + kg];
            uint2 u1 = xb2[(size_t)__float_as_int(e1.y) * 16 + kg];
            uint2 u2 = xb2[(size_t)__float_as_int(e2.y) * 16 + kg];
            uint2 u3 = xb2[(size_t)__float_as_int(e3.y) * 16 + kg];
            den += ((w0 + w1v) + (w2v + w3v));
            ACC4(u0, w0);
            ACC4(u1, w1v);
            ACC4(u2, w2v);
            ACC4(u3, w3v);
        }
        __builtin_amdgcn_wave_barrier();
    }
#undef ACC4

    const float inv = 1.f / (den + 1e-16f);
    uint p0 = (uint)f2bf(acc.x * inv) | ((uint)f2bf(acc.y * inv) << 16);
    uint p1 = (uint)f2bf(acc.z * inv) | ((uint)f2bf(acc.w * inv) << 16);
    uint2 ov = {p0, p1};
    *(uint2*)&AGG[(size_t)node * 256 + (size_t)l * 4] = ov;
}

// ---------------- recovery GEMM (K=256) on matrix cores --------------------

template <bool F32OUT>
__global__ __launch_bounds__(256) void gemm256_mfma(
    const ushortx* __restrict__ AGG, const ushortx* __restrict__ wfrag,
    const float* __restrict__ bias, ushortx* __restrict__ Xb,
    float* __restrict__ OUTF) {
    __shared__ ushortx wt[4][8][64][8];    // [ct][kb][lane][j]  (32 KB)
    const int tid = threadIdx.x;
    const int l = tid & 63, wv = tid >> 6;
    const int n = l & 15, q = l >> 4;

    {
        const uint4* src = (const uint4*)wfrag;
        uint4* dst = (uint4*)&wt[0][0][0][0];
#pragma unroll
        for (int i = 0; i < 8; ++i) dst[i * 256 + tid] = src[i * 256 + tid];
    }
    __syncthreads();

    for (int row0 = blockIdx.x * 64 + wv * 16; row0 < NN; row0 += gridDim.x * 64) {
        f32x4 acc[4] = {{0.f, 0.f, 0.f, 0.f}, {0.f, 0.f, 0.f, 0.f},
                        {0.f, 0.f, 0.f, 0.f}, {0.f, 0.f, 0.f, 0.f}};
#pragma unroll
        for (int kb = 0; kb < 8; ++kb) {
            short8 a = *(const short8*)&AGG[(size_t)(row0 + n) * 256 + kb * 32 + q * 8];
#pragma unroll
            for (int ct = 0; ct < 4; ++ct) {
                short8 b = *(const short8*)&wt[ct][kb][l][0];
                acc[ct] = __builtin_amdgcn_mfma_f32_16x16x32_bf16(b, a, acc[ct], 0, 0, 0);
            }
        }
        const int row = row0 + n;
#pragma unroll
        for (int ct = 0; ct < 4; ++ct) {
            const int col = ct * 16 + q * 4;
            float4 b4 = ((const float4*)bias)[ct * 4 + q];
            float o0 = fmaxf(acc[ct][0] + b4.x, 0.f);
            float o1 = fmaxf(acc[ct][1] + b4.y, 0.f);
            float o2 = fmaxf(acc[ct][2] + b4.z, 0.f);
            float o3 = fmaxf(acc[ct][3] + b4.w, 0.f);
            if constexpr (F32OUT) {
                float4 ov = {o0, o1, o2, o3};
                *(float4*)&OUTF[(size_t)row * 64 + col] = ov;
            } else {
                uint p0 = (uint)f2bf(o0) | ((uint)f2bf(o1) << 16);
                uint p1 = (uint)f2bf(o2) | ((uint)f2bf(o3) << 16);
                uint2 ov = {p0, p1};
                *(uint2*)&Xb[(size_t)row * 64 + col] = ov;
            }
        }
    }
}

// ---------------- graph mean-pool + final linear (no atomics) --------------

__global__ __launch_bounds__(256) void pool_graph(
    const float* __restrict__ OUTF, const int* __restrict__ batch,
    const float* __restrict__ lw, const float* __restrict__ lb,
    float* __restrict__ out) {
    const int g = blockIdx.x * 4 + (threadIdx.x >> 6);
    const int l = threadIdx.x & 63;
    if (g >= GG) return;
    int lo = 0, hi = NN;
    while (lo < hi) { int mid = (lo + hi) >> 1; if (batch[mid] < g) lo = mid + 1; else hi = mid; }
    int lo2 = lo, hi2 = NN;
    while (lo2 < hi2) { int mid = (lo2 + hi2) >> 1; if (batch[mid] < g + 1) lo2 = mid + 1; else hi2 = mid; }
    float s = 0.f;
    int nn = lo;
    for (; nn + 4 <= lo2; nn += 4) {
        float a0 = OUTF[(size_t)(nn + 0) * 64 + l];
        float a1 = OUTF[(size_t)(nn + 1) * 64 + l];
        float a2 = OUTF[(size_t)(nn + 2) * 64 + l];
        float a3 = OUTF[(size_t)(nn + 3) * 64 + l];
        s += (a0 + a1) + (a2 + a3);
    }
    for (; nn < lo2; ++nn) s += OUTF[(size_t)nn * 64 + l];
    const float cntf = fmaxf((float)(lo2 - lo), 1.f);
    float v = s / cntf * lw[l];
#pragma unroll
    for (int m = 32; m; m >>= 1) v += __shfl_xor(v, m, 64);
    if (l == 0) out[g] = v + lb[0];
}

// ---------------- launch ----------------

extern "C" void kernel_launch(void* const* d_in, const int* in_sizes, int n_in,
                              void* d_out, int out_size, void* d_ws, size_t ws_size,
                              hipStream_t stream) {
    const float* x     = (const float*)d_in[0];
    const int*   ei    = (const int*)d_in[1];
    const int*   batch = (const int*)d_in[2];
    const float* W1  = (const float*)d_in[3];
    const float* as1 = (const float*)d_in[4];
    const float* ad1 = (const float*)d_in[5];
    const float* b1  = (const float*)d_in[6];
    const float* W2  = (const float*)d_in[7];
    const float* as2 = (const float*)d_in[8];
    const float* ad2 = (const float*)d_in[9];
    const float* b2  = (const float*)d_in[10];
    const float* W3  = (const float*)d_in[11];
    const float* as3 = (const float*)d_in[12];
    const float* ad3 = (const float*)d_in[13];
    const float* b3  = (const float*)d_in[14];
    const float* lw  = (const float*)d_in[15];
    const float* lb  = (const float*)d_in[16];
    float* out = (float*)d_out;

    char* p = (char*)d_ws;
    auto carve = [&](size_t bytes) -> void* {
        void* r = (void*)p;
        p += (bytes + 255) & ~(size_t)255;
        return r;
    };
    int*     off    = (int*)carve((NN + 4) * sizeof(int));
    int*     deg    = (int*)carve(NN * sizeof(int));
    int*     rank   = (int*)carve((size_t)(EE + NN) * sizeof(int));
    int*     bsum   = (int*)carve(NB * sizeof(int));
    int*     boff   = (int*)carve(NB * sizeof(int));
    int*     csr    = (int*)carve((size_t)(EE + NN) * sizeof(int));
    ushortx* aggb   = (ushortx*)carve((size_t)NN * 256 * sizeof(ushortx));  // 51.2 MB
    float*   agg1   = (float*)carve((size_t)NN * 64 * sizeof(float));       // 25.6 MB
    ushortx* xb1    = (ushortx*)carve((size_t)NN * 64 * sizeof(ushortx));   // 12.8 MB
    float*   outf   = (float*)carve((size_t)NN * 64 * sizeof(float));       // 25.6 MB
    float*   als    = (float*)carve((size_t)NN * 4 * sizeof(float));
    float*   ald    = (float*)carve((size_t)NN * 4 * sizeof(float));
    float*   va1    = (float*)carve(9 * 8 * sizeof(float));
    float*   va2    = (float*)carve(64 * 8 * sizeof(float));
    float*   va3    = (float*)carve(64 * 8 * sizeof(float));
    ushortx* wf2    = (ushortx*)carve(16384 * sizeof(ushortx));
    ushortx* wf3    = (ushortx*)carve(16384 * sizeof(ushortx));
    // xb2 aliases agg1 (agg1 dead after gemm36; xb2 first written by L2 GEMM)
    ushortx* xb2 = (ushortx*)agg1;

    hipMemsetAsync(deg, 0, NN * sizeof(int), stream);

    const int etot = EE + NN;
    const int eblocks = (etot + 255) / 256;
    hist_kernel<<<eblocks, 256, 0, stream>>>(ei, deg, rank);
    scan_blk<<<NB, 256, 0, stream>>>(deg, bsum);
    scan_mid<<<1, 128, 0, stream>>>(bsum, boff, off);
    scan_fin<<<NB, 256, 0, stream>>>(deg, boff, off);
    fill_sharded<<<2048, 256, 0, stream>>>(ei, off, rank, csr);

    prep_all<<<133, 256, 0, stream>>>(W1, as1, ad1, W2, as2, ad2, W3, as3, ad3,
                                      va1, va2, va3, wf2, wf3);

    const int ablocks = (NN + 3) / 4;
    const int nblocks = (NN + 255) / 256;

    // layer 1 (fp32 exact: aggregate x, then K=36 GEMM)
    att_gemv<9><<<nblocks, 256, 0, stream>>>(x, va1, als, ald);
    aggregate_x1<<<ablocks, 256, 0, stream>>>(x, als, ald, off, csr, agg1);
    gemm36<<<2048, 256, 0, stream>>>(agg1, W1, b1, xb1);

    // layer 2
    att_gemv_b<<<nblocks, 256, 0, stream>>>(xb1, va2, als, ald);
    aggregate_xb<<<ablocks, 256, 0, stream>>>(xb1, als, ald, off, csr, aggb);
    gemm256_mfma<false><<<512, 256, 0, stream>>>(aggb, wf2, b2, xb2, nullptr);

    // layer 3 (fp32 node outputs; pooling in dedicated kernel, no atomics)
    att_gemv_b<<<nblocks, 256, 0, stream>>>(xb2, va3, als, ald);
    aggregate_xb<<<ablocks, 256, 0, stream>>>(xb2, als, ald, off, csr, aggb);
    gemm256_mfma<true><<<512, 256, 0, stream>>>(aggb, wf3, b3, nullptr, outf);

    pool_graph<<<(GG + 3) / 4, 256, 0, stream>>>(outf, batch, lw, lb, out);
}

// Round 9
// 334.708 us; speedup vs baseline: 2.4809x; 1.1483x over previous
//
#include <hip/hip_runtime.h>
#include <hip/hip_bf16.h>

#define NN 100000
#define EE 800000
#define HH 4
#define CC 64
#define GG 2000
#define NB 98           // scan blocks: ceil((NN/4)/256)

typedef unsigned short ushortx;
typedef __attribute__((ext_vector_type(8))) short short8;
typedef __attribute__((ext_vector_type(4))) float f32x4;

// ---------------- CSR build ----------------
// hist: atomicAdd's RETURN is the edge's within-dst rank -- store it
// (coalesced). fill then needs NO atomic: p = off[d] + rank[e].

__global__ void hist_kernel(const int* __restrict__ ei, int* __restrict__ deg,
                            int* __restrict__ rank) {
    int e = blockIdx.x * 256 + threadIdx.x;
    const int tot = EE + NN;
    if (e < tot) {
        int d = (e < EE) ? ei[EE + e] : (e - EE);
        rank[e] = atomicAdd(&deg[d], 1);
    }
}

__global__ __launch_bounds__(256) void scan_blk(const int* __restrict__ deg,
                                                int* __restrict__ bsum) {
    const int t = threadIdx.x;
    const int idx4 = blockIdx.x * 256 + t;
    int4 v = {0, 0, 0, 0};
    if (idx4 < NN / 4) v = ((const int4*)deg)[idx4];
    int s = v.x + v.y + v.z + v.w;
#pragma unroll
    for (int m = 32; m; m >>= 1) s += __shfl_xor(s, m, 64);
    __shared__ int ws[4];
    if ((t & 63) == 0) ws[t >> 6] = s;
    __syncthreads();
    if (t == 0) bsum[blockIdx.x] = ws[0] + ws[1] + ws[2] + ws[3];
}

__global__ void scan_mid(const int* __restrict__ bsum, int* __restrict__ boff,
                         int* __restrict__ off) {
    __shared__ int sh[128];
    const int t = threadIdx.x;
    int v = (t < NB) ? bsum[t] : 0;
    sh[t] = v;
    __syncthreads();
    for (int d = 1; d < 128; d <<= 1) {
        int u = (t >= d) ? sh[t - d] : 0;
        __syncthreads();
        sh[t] += u;
        __syncthreads();
    }
    if (t < NB) boff[t] = sh[t] - v;
    if (t == NB - 1) off[NN] = sh[t];
}

__global__ __launch_bounds__(256) void scan_fin(const int* __restrict__ deg,
                                                const int* __restrict__ boff,
                                                int* __restrict__ off) {
    const int t = threadIdx.x;
    const int idx4 = blockIdx.x * 256 + t;
    int4 v = {0, 0, 0, 0};
    if (idx4 < NN / 4) v = ((const int4*)deg)[idx4];
    int s = v.x + v.y + v.z + v.w;
    const int lane = t & 63, w = t >> 6;
    int inc = s;
#pragma unroll
    for (int d = 1; d < 64; d <<= 1) {
        int u = __shfl_up(inc, d, 64);
        if (lane >= d) inc += u;
    }
    __shared__ int ws[4];
    if (lane == 63) ws[w] = inc;
    __syncthreads();
    int woff = 0;
    for (int i = 0; i < w; ++i) woff += ws[i];
    int excl = inc - s + woff + boff[blockIdx.x];
    if (idx4 < NN / 4) {
        int4 o;
        o.x = excl;
        o.y = o.x + v.x;
        o.z = o.y + v.y;
        o.w = o.z + v.z;
        ((int4*)off)[idx4] = o;
    }
}

// XCD-sharded fill (R5-proven): no atomics, contiguous per-shard writes.
__global__ __launch_bounds__(256) void fill_sharded(
    const int* __restrict__ ei, const int* __restrict__ off,
    const int* __restrict__ rank, int* __restrict__ csr_src) {
    const int shard = blockIdx.x & 7;
    const int wblk = blockIdx.x >> 3;
    const int lo = shard * (NN / 8);
    const int hi = lo + (NN / 8);
    const int tot = EE + NN;
    for (int e = wblk * 256 + threadIdx.x; e < tot; e += 256 * 256) {
        int d = (e < EE) ? ei[EE + e] : (e - EE);
        if (d >= lo && d < hi) {
            int s = (e < EE) ? ei[e] : (e - EE);
            csr_src[off[d] + rank[e]] = s;
        }
    }
}

__device__ __forceinline__ ushortx f2bf(float v) {
    __hip_bfloat16 b = __float2bfloat16(v);
    return *reinterpret_cast<ushortx*>(&b);
}

// ---------------- parameter precompute (single merged kernel) ---------------

__device__ __forceinline__ void do_va(const float* __restrict__ W,
                                      const float* __restrict__ as_,
                                      const float* __restrict__ ad_,
                                      float* __restrict__ va, int K, int id) {
    if (id >= K * 8) return;
    int k = id >> 3, comp = id & 7;
    int h = comp & 3, sd = comp >> 2;
    const float* a = sd ? ad_ : as_;
    const float* wrow = W + k * 256 + h * 64;
    const float* arow = a + h * 64;
    float s = 0.f;
    for (int c = 0; c < 64; ++c) s = fmaf(wrow[c], arow[c], s);
    va[k * 8 + comp] = s;
}

__device__ __forceinline__ void do_wfrag(const float* __restrict__ W,
                                         ushortx* __restrict__ wfrag, int i) {
    if (i >= 16384) return;
    int j = i & 7, lane = (i >> 3) & 63, kb = (i >> 9) & 7, ct = i >> 12;
    int c = ct * 16 + (lane & 15);
    int kap = kb * 32 + (lane >> 4) * 8 + j;
    int h = kap >> 6, kw = kap & 63;
    wfrag[i] = f2bf(W[kw * 256 + h * 64 + c] * 0.25f);
}

__global__ void prep_all(
    const float* __restrict__ W1, const float* __restrict__ as1,
    const float* __restrict__ ad1, const float* __restrict__ W2,
    const float* __restrict__ as2, const float* __restrict__ ad2,
    const float* __restrict__ W3, const float* __restrict__ as3,
    const float* __restrict__ ad3, float* __restrict__ va1,
    float* __restrict__ va2, float* __restrict__ va3,
    ushortx* __restrict__ wf2, ushortx* __restrict__ wf3) {
    const int b = blockIdx.x, tid = threadIdx.x;
    if (b == 0) do_va(W1, as1, ad1, va1, 9, tid);
    else if (b <= 2) do_va(W2, as2, ad2, va2, 64, (b - 1) * 256 + tid);
    else if (b <= 4) do_va(W3, as3, ad3, va3, 64, (b - 3) * 256 + tid);
    else if (b <= 68) do_wfrag(W2, wf2, (b - 5) * 256 + tid);
    else do_wfrag(W3, wf3, (b - 69) * 256 + tid);
}

// ALS/ALD from fp32 X (layer 1, K=9).
template <int K>
__global__ __launch_bounds__(256) void att_gemv(
    const float* __restrict__ X, const float* __restrict__ va,
    float* __restrict__ ALS, float* __restrict__ ALD) {
    __shared__ float vs[K][8];
    const int tid = threadIdx.x;
    for (int i = tid; i < K * 8; i += 256) vs[i >> 3][i & 7] = va[i];
    __syncthreads();
    int n = blockIdx.x * 256 + tid;
    if (n >= NN) return;
    const float* xp = X + (size_t)n * K;
    float s0 = 0, s1 = 0, s2 = 0, s3 = 0, d0 = 0, d1 = 0, d2 = 0, d3 = 0;
#pragma unroll
    for (int k = 0; k < K; ++k) {
        float x1 = xp[k];
        const float4 vsv = *(const float4*)&vs[k][0];
        const float4 vdv = *(const float4*)&vs[k][4];
        s0 = fmaf(x1, vsv.x, s0); s1 = fmaf(x1, vsv.y, s1);
        s2 = fmaf(x1, vsv.z, s2); s3 = fmaf(x1, vsv.w, s3);
        d0 = fmaf(x1, vdv.x, d0); d1 = fmaf(x1, vdv.y, d1);
        d2 = fmaf(x1, vdv.z, d2); d3 = fmaf(x1, vdv.w, d3);
    }
    float4 so = {s0, s1, s2, s3}, dd = {d0, d1, d2, d3};
    ((float4*)ALS)[n] = so;
    ((float4*)ALD)[n] = dd;
}

// ALS/ALD from bf16 X (layers 2,3, K=64).
__global__ __launch_bounds__(256) void att_gemv_b(
    const ushortx* __restrict__ Xb, const float* __restrict__ va,
    float* __restrict__ ALS, float* __restrict__ ALD) {
    __shared__ float vs[64][8];
    const int tid = threadIdx.x;
    for (int i = tid; i < 64 * 8; i += 256) vs[i >> 3][i & 7] = va[i];
    __syncthreads();
    int n = blockIdx.x * 256 + tid;
    if (n >= NN) return;
    const uint4* xp = (const uint4*)(Xb + (size_t)n * 64);
    float s0 = 0, s1 = 0, s2 = 0, s3 = 0, d0 = 0, d1 = 0, d2 = 0, d3 = 0;
#pragma unroll
    for (int qq = 0; qq < 8; ++qq) {
        uint4 u = xp[qq];
        float xv[8];
        xv[0] = __uint_as_float(u.x << 16);
        xv[1] = __uint_as_float(u.x & 0xFFFF0000u);
        xv[2] = __uint_as_float(u.y << 16);
        xv[3] = __uint_as_float(u.y & 0xFFFF0000u);
        xv[4] = __uint_as_float(u.z << 16);
        xv[5] = __uint_as_float(u.z & 0xFFFF0000u);
        xv[6] = __uint_as_float(u.w << 16);
        xv[7] = __uint_as_float(u.w & 0xFFFF0000u);
#pragma unroll
        for (int j = 0; j < 8; ++j) {
            const int k = qq * 8 + j;
            const float4 vsv = *(const float4*)&vs[k][0];
            const float4 vdv = *(const float4*)&vs[k][4];
            s0 = fmaf(xv[j], vsv.x, s0); s1 = fmaf(xv[j], vsv.y, s1);
            s2 = fmaf(xv[j], vsv.z, s2); s3 = fmaf(xv[j], vsv.w, s3);
            d0 = fmaf(xv[j], vdv.x, d0); d1 = fmaf(xv[j], vdv.y, d1);
            d2 = fmaf(xv[j], vdv.z, d2); d3 = fmaf(xv[j], vdv.w, d3);
        }
    }
    float4 so = {s0, s1, s2, s3}, dd = {d0, d1, d2, d3};
    ((float4*)ALS)[n] = so;
    ((float4*)ALD)[n] = dd;
}

// ------------- shared weight-phase helper (leaky + exp, per lane) ----------
__device__ __forceinline__ float4 edge_w4(const float4 a, const float4 aldv) {
    float vx = a.x + aldv.x, vy = a.y + aldv.y,
          vz = a.z + aldv.z, vw = a.w + aldv.w;
    vx = (vx >= 0.f) ? vx : 0.2f * vx;
    vy = (vy >= 0.f) ? vy : 0.2f * vy;
    vz = (vz >= 0.f) ? vz : 0.2f * vz;
    vw = (vw >= 0.f) ? vw : 0.2f * vw;
    float4 w;
    w.x = __expf(vx); w.y = __expf(vy); w.z = __expf(vz); w.w = __expf(vw);
    return w;
}

// ---------------- layer-1: aggregate raw x (4 nodes/wave, fp32 exact) ------
// Wave = 4 nodes x 16 lanes. Lane (g, k): node g, channel k (k<9 active),
// accumulates ALL 4 heads (float4 acc). Weight phase: 64 lanes cover 4 nodes
// x 16 edge slots at once (fixed cost /4). Zero-weight padded slots make the
// wave-max edge loop exact. den per (node,head) via 4-step in-group butterfly.

__global__ __launch_bounds__(256) void aggregate_x1(
    const float* __restrict__ X, const float* __restrict__ ALS,
    const float* __restrict__ ALD, const int* __restrict__ off,
    const int* __restrict__ csr_src, float* __restrict__ AGG1) {
    __shared__ float4 wtab4[4][4][21];   // [wave][group][slot pad21]
    __shared__ int    svtab[4][4][21];
    const int wv = threadIdx.x >> 6;
    const int l = threadIdx.x & 63;
    const int g = l >> 4, kg = l & 15;
    const int node = blockIdx.x * 16 + wv * 4 + g;
    const bool nvalid = node < NN;
    const bool act = (kg < 9);
    int beg = 0, end = 0;
    if (nvalid) { beg = off[node]; end = off[node + 1]; }
    int md = end - beg;
    md = max(md, __shfl_xor(md, 16, 64));
    md = max(md, __shfl_xor(md, 32, 64));
    float4 aldv = {0.f, 0.f, 0.f, 0.f};
    if (nvalid) aldv = ((const float4*)ALD)[node];
    const float4* wt = &wtab4[wv][g][0];
    const int* st = &svtab[wv][g][0];
    float4 acc = {0.f, 0.f, 0.f, 0.f};       // 4 heads, channel kg
    float4 den4 = {0.f, 0.f, 0.f, 0.f};

    for (int c0 = 0; c0 < md; c0 += 16) {
        const int jj = beg + c0 + kg;
        int sv = 0;
        float4 w4 = {0.f, 0.f, 0.f, 0.f};
        if (nvalid && jj < end) {
            sv = csr_src[jj];
            w4 = edge_w4(((const float4*)ALS)[sv], aldv);
        }
        den4.x += w4.x; den4.y += w4.y; den4.z += w4.z; den4.w += w4.w;
        wtab4[wv][g][kg] = w4;
        svtab[wv][g][kg] = sv;
        __builtin_amdgcn_wave_barrier();
        asm volatile("s_waitcnt lgkmcnt(0)" ::: "memory");
        __builtin_amdgcn_sched_barrier(0);

        const int mc = min(16, md - c0);
        for (int t = 0; t < mc; t += 4) {
            float4 wA = wt[t + 0]; int sA = st[t + 0];
            float4 wB = wt[t + 1]; int sB = st[t + 1];
            float4 wC = wt[t + 2]; int sC = st[t + 2];
            float4 wD = wt[t + 3]; int sD = st[t + 3];
            float vA = 0.f, vB = 0.f, vC = 0.f, vD = 0.f;
            if (act) {
                vA = X[(size_t)sA * 9 + kg];
                vB = X[(size_t)sB * 9 + kg];
                vC = X[(size_t)sC * 9 + kg];
                vD = X[(size_t)sD * 9 + kg];
            }
            acc.x = fmaf(wA.x, vA, acc.x); acc.y = fmaf(wA.y, vA, acc.y);
            acc.z = fmaf(wA.z, vA, acc.z); acc.w = fmaf(wA.w, vA, acc.w);
            acc.x = fmaf(wB.x, vB, acc.x); acc.y = fmaf(wB.y, vB, acc.y);
            acc.z = fmaf(wB.z, vB, acc.z); acc.w = fmaf(wB.w, vB, acc.w);
            acc.x = fmaf(wC.x, vC, acc.x); acc.y = fmaf(wC.y, vC, acc.y);
            acc.z = fmaf(wC.z, vC, acc.z); acc.w = fmaf(wC.w, vC, acc.w);
            acc.x = fmaf(wD.x, vD, acc.x); acc.y = fmaf(wD.y, vD, acc.y);
            acc.z = fmaf(wD.z, vD, acc.z); acc.w = fmaf(wD.w, vD, acc.w);
        }
        __builtin_amdgcn_wave_barrier();
    }

#pragma unroll
    for (int m = 1; m <= 8; m <<= 1) {
        den4.x += __shfl_xor(den4.x, m, 64);
        den4.y += __shfl_xor(den4.y, m, 64);
        den4.z += __shfl_xor(den4.z, m, 64);
        den4.w += __shfl_xor(den4.w, m, 64);
    }
    if (nvalid && act) {
        float i0 = 1.f / (den4.x + 1e-16f);
        float i1 = 1.f / (den4.y + 1e-16f);
        float i2 = 1.f / (den4.z + 1e-16f);
        float i3 = 1.f / (den4.w + 1e-16f);
        float* o = AGG1 + (size_t)node * 64;
        o[0 * 16 + kg] = acc.x * i0;
        o[1 * 16 + kg] = acc.y * i1;
        o[2 * 16 + kg] = acc.z * i2;
        o[3 * 16 + kg] = acc.w * i3;
    }
}

// ---------------- layer-1 recovery GEMM: out = relu(1/4 AGG1.Wc + b) -------

__global__ __launch_bounds__(256) void gemm36(
    const float* __restrict__ AGG1, const float* __restrict__ W1,
    const float* __restrict__ b1, ushortx* __restrict__ Xb) {
    const int c = threadIdx.x & 63;
    const int wv = threadIdx.x >> 6;
    float wreg[36];
#pragma unroll
    for (int h = 0; h < 4; ++h)
#pragma unroll
        for (int k = 0; k < 9; ++k)
            wreg[h * 9 + k] = W1[k * 256 + h * 64 + c] * 0.25f;
    const float bc = b1[c];
    for (int row = blockIdx.x * 4 + wv; row < NN; row += gridDim.x * 4) {
        const float* xr = AGG1 + (size_t)row * 64;
        float s = 0.f;
#pragma unroll
        for (int h = 0; h < 4; ++h)
#pragma unroll
            for (int k = 0; k < 9; ++k)
                s = fmaf(wreg[h * 9 + k], xr[h * 16 + k], s);
        s = fmaxf(s + bc, 0.f);
        Xb[(size_t)row * 64 + c] = f2bf(s);
    }
}

// ---------------- layers 2,3: aggregate bf16 X (4 nodes/wave) --------------
// Lane (g, c4): node g, channel-quad c4 (4 bf16 ch), all 4 heads in 4 float4
// accumulators (16 f32, no cross-lane acc reduction). Per t-iteration the
// wave processes 4 edges (one per group): 2 LDS reads + 1 uint2 gather +
// 4 unpack + 16 fma. Zero-weight padded slots (sv clamped 0) keep the
// wave-max loop exact; per-(node,head) den via in-group butterfly.

__global__ __launch_bounds__(256) void aggregate_xb(
    const ushortx* __restrict__ Xb, const float* __restrict__ ALS,
    const float* __restrict__ ALD, const int* __restrict__ off,
    const int* __restrict__ csr_src, ushortx* __restrict__ AGG) {
    __shared__ float4 wtab4[4][4][21];   // [wave][group][slot pad21]
    __shared__ int    svtab[4][4][21];
    const int wv = threadIdx.x >> 6;
    const int l = threadIdx.x & 63;
    const int g = l >> 4, c4 = l & 15;
    const int node = blockIdx.x * 16 + wv * 4 + g;
    const bool nvalid = node < NN;
    int beg = 0, end = 0;
    if (nvalid) { beg = off[node]; end = off[node + 1]; }
    int md = end - beg;
    md = max(md, __shfl_xor(md, 16, 64));
    md = max(md, __shfl_xor(md, 32, 64));
    float4 aldv = {0.f, 0.f, 0.f, 0.f};
    if (nvalid) aldv = ((const float4*)ALD)[node];
    const uint2* xb2 = (const uint2*)Xb;   // row = 16 uint2 (64 bf16)
    const float4* wt = &wtab4[wv][g][0];
    const int* st = &svtab[wv][g][0];
    float4 a0 = {0.f, 0.f, 0.f, 0.f};      // head 0, ch c4*4..+3
    float4 a1 = {0.f, 0.f, 0.f, 0.f};
    float4 a2 = {0.f, 0.f, 0.f, 0.f};
    float4 a3 = {0.f, 0.f, 0.f, 0.f};
    float4 den4 = {0.f, 0.f, 0.f, 0.f};

#define UPD(uu, ww)                                                 \
    {                                                               \
        float c0v = __uint_as_float((uu).x << 16);                  \
        float c1v = __uint_as_float((uu).x & 0xFFFF0000u);          \
        float c2v = __uint_as_float((uu).y << 16);                  \
        float c3v = __uint_as_float((uu).y & 0xFFFF0000u);          \
        a0.x = fmaf((ww).x, c0v, a0.x); a0.y = fmaf((ww).x, c1v, a0.y); \
        a0.z = fmaf((ww).x, c2v, a0.z); a0.w = fmaf((ww).x, c3v, a0.w); \
        a1.x = fmaf((ww).y, c0v, a1.x); a1.y = fmaf((ww).y, c1v, a1.y); \
        a1.z = fmaf((ww).y, c2v, a1.z); a1.w = fmaf((ww).y, c3v, a1.w); \
        a2.x = fmaf((ww).z, c0v, a2.x); a2.y = fmaf((ww).z, c1v, a2.y); \
        a2.z = fmaf((ww).z, c2v, a2.z); a2.w = fmaf((ww).z, c3v, a2.w); \
        a3.x = fmaf((ww).w, c0v, a3.x); a3.y = fmaf((ww).w, c1v, a3.y); \
        a3.z = fmaf((ww).w, c2v, a3.z); a3.w = fmaf((ww).w, c3v, a3.w); \
    }

    for (int c0 = 0; c0 < md; c0 += 16) {
        const int jj = beg + c0 + c4;
        int sv = 0;
        float4 w4 = {0.f, 0.f, 0.f, 0.f};
        if (nvalid && jj < end) {
            sv = csr_src[jj];
            w4 = edge_w4(((const float4*)ALS)[sv], aldv);
        }
        den4.x += w4.x; den4.y += w4.y; den4.z += w4.z; den4.w += w4.w;
        wtab4[wv][g][c4] = w4;
        svtab[wv][g][c4] = sv;
        __builtin_amdgcn_wave_barrier();
        asm volatile("s_waitcnt lgkmcnt(0)" ::: "memory");
        __builtin_amdgcn_sched_barrier(0);

        const int mc = min(16, md - c0);
        for (int t = 0; t < mc; t += 4) {
            float4 wA = wt[t + 0]; int sA = st[t + 0];
            float4 wB = wt[t + 1]; int sB = st[t + 1];
            float4 wC = wt[t + 2]; int sC = st[t + 2];
            float4 wD = wt[t + 3]; int sD = st[t + 3];
            uint2 uA = xb2[(size_t)sA * 16 + c4];
            uint2 uB = xb2[(size_t)sB * 16 + c4];
            uint2 uC = xb2[(size_t)sC * 16 + c4];
            uint2 uD = xb2[(size_t)sD * 16 + c4];
            UPD(uA, wA);
            UPD(uB, wB);
            UPD(uC, wC);
            UPD(uD, wD);
        }
        __builtin_amdgcn_wave_barrier();
    }
#undef UPD

#pragma unroll
    for (int m = 1; m <= 8; m <<= 1) {
        den4.x += __shfl_xor(den4.x, m, 64);
        den4.y += __shfl_xor(den4.y, m, 64);
        den4.z += __shfl_xor(den4.z, m, 64);
        den4.w += __shfl_xor(den4.w, m, 64);
    }
    if (nvalid) {
        float i0 = 1.f / (den4.x + 1e-16f);
        float i1 = 1.f / (den4.y + 1e-16f);
        float i2 = 1.f / (den4.z + 1e-16f);
        float i3 = 1.f / (den4.w + 1e-16f);
        ushortx* orow = AGG + (size_t)node * 256;
        uint p0, p1;
        p0 = (uint)f2bf(a0.x * i0) | ((uint)f2bf(a0.y * i0) << 16);
        p1 = (uint)f2bf(a0.z * i0) | ((uint)f2bf(a0.w * i0) << 16);
        *(uint2*)&orow[0 * 64 + c4 * 4] = uint2{p0, p1};
        p0 = (uint)f2bf(a1.x * i1) | ((uint)f2bf(a1.y * i1) << 16);
        p1 = (uint)f2bf(a1.z * i1) | ((uint)f2bf(a1.w * i1) << 16);
        *(uint2*)&orow[1 * 64 + c4 * 4] = uint2{p0, p1};
        p0 = (uint)f2bf(a2.x * i2) | ((uint)f2bf(a2.y * i2) << 16);
        p1 = (uint)f2bf(a2.z * i2) | ((uint)f2bf(a2.w * i2) << 16);
        *(uint2*)&orow[2 * 64 + c4 * 4] = uint2{p0, p1};
        p0 = (uint)f2bf(a3.x * i3) | ((uint)f2bf(a3.y * i3) << 16);
        p1 = (uint)f2bf(a3.z * i3) | ((uint)f2bf(a3.w * i3) << 16);
        *(uint2*)&orow[3 * 64 + c4 * 4] = uint2{p0, p1};
    }
}

// ---------------- recovery GEMM (K=256) on matrix cores --------------------

template <bool F32OUT>
__global__ __launch_bounds__(256) void gemm256_mfma(
    const ushortx* __restrict__ AGG, const ushortx* __restrict__ wfrag,
    const float* __restrict__ bias, ushortx* __restrict__ Xb,
    float* __restrict__ OUTF) {
    __shared__ ushortx wt[4][8][64][8];    // [ct][kb][lane][j]  (32 KB)
    const int tid = threadIdx.x;
    const int l = tid & 63, wv = tid >> 6;
    const int n = l & 15, q = l >> 4;

    {
        const uint4* src = (const uint4*)wfrag;
        uint4* dst = (uint4*)&wt[0][0][0][0];
#pragma unroll
        for (int i = 0; i < 8; ++i) dst[i * 256 + tid] = src[i * 256 + tid];
    }
    __syncthreads();

    for (int row0 = blockIdx.x * 64 + wv * 16; row0 < NN; row0 += gridDim.x * 64) {
        f32x4 acc[4] = {{0.f, 0.f, 0.f, 0.f}, {0.f, 0.f, 0.f, 0.f},
                        {0.f, 0.f, 0.f, 0.f}, {0.f, 0.f, 0.f, 0.f}};
#pragma unroll
        for (int kb = 0; kb < 8; ++kb) {
            short8 a = *(const short8*)&AGG[(size_t)(row0 + n) * 256 + kb * 32 + q * 8];
#pragma unroll
            for (int ct = 0; ct < 4; ++ct) {
                short8 b = *(const short8*)&wt[ct][kb][l][0];
                acc[ct] = __builtin_amdgcn_mfma_f32_16x16x32_bf16(b, a, acc[ct], 0, 0, 0);
            }
        }
        const int row = row0 + n;
#pragma unroll
        for (int ct = 0; ct < 4; ++ct) {
            const int col = ct * 16 + q * 4;
            float4 b4 = ((const float4*)bias)[ct * 4 + q];
            float o0 = fmaxf(acc[ct][0] + b4.x, 0.f);
            float o1 = fmaxf(acc[ct][1] + b4.y, 0.f);
            float o2 = fmaxf(acc[ct][2] + b4.z, 0.f);
            float o3 = fmaxf(acc[ct][3] + b4.w, 0.f);
            if constexpr (F32OUT) {
                float4 ov = {o0, o1, o2, o3};
                *(float4*)&OUTF[(size_t)row * 64 + col] = ov;
            } else {
                uint p0 = (uint)f2bf(o0) | ((uint)f2bf(o1) << 16);
                uint p1 = (uint)f2bf(o2) | ((uint)f2bf(o3) << 16);
                uint2 ov = {p0, p1};
                *(uint2*)&Xb[(size_t)row * 64 + col] = ov;
            }
        }
    }
}

// ---------------- graph mean-pool + final linear (no atomics) --------------

__global__ __launch_bounds__(256) void pool_graph(
    const float* __restrict__ OUTF, const int* __restrict__ batch,
    const float* __restrict__ lw, const float* __restrict__ lb,
    float* __restrict__ out) {
    const int g = blockIdx.x * 4 + (threadIdx.x >> 6);
    const int l = threadIdx.x & 63;
    if (g >= GG) return;
    int lo = 0, hi = NN;
    while (lo < hi) { int mid = (lo + hi) >> 1; if (batch[mid] < g) lo = mid + 1; else hi = mid; }
    int lo2 = lo, hi2 = NN;
    while (lo2 < hi2) { int mid = (lo2 + hi2) >> 1; if (batch[mid] < g + 1) lo2 = mid + 1; else hi2 = mid; }
    float s = 0.f;
    int nn = lo;
    for (; nn + 4 <= lo2; nn += 4) {
        float a0 = OUTF[(size_t)(nn + 0) * 64 + l];
        float a1 = OUTF[(size_t)(nn + 1) * 64 + l];
        float a2 = OUTF[(size_t)(nn + 2) * 64 + l];
        float a3 = OUTF[(size_t)(nn + 3) * 64 + l];
        s += (a0 + a1) + (a2 + a3);
    }
    for (; nn < lo2; ++nn) s += OUTF[(size_t)nn * 64 + l];
    const float cntf = fmaxf((float)(lo2 - lo), 1.f);
    float v = s / cntf * lw[l];
#pragma unroll
    for (int m = 32; m; m >>= 1) v += __shfl_xor(v, m, 64);
    if (l == 0) out[g] = v + lb[0];
}

// ---------------- launch ----------------

extern "C" void kernel_launch(void* const* d_in, const int* in_sizes, int n_in,
                              void* d_out, int out_size, void* d_ws, size_t ws_size,
                              hipStream_t stream) {
    const float* x     = (const float*)d_in[0];
    const int*   ei    = (const int*)d_in[1];
    const int*   batch = (const int*)d_in[2];
    const float* W1  = (const float*)d_in[3];
    const float* as1 = (const float*)d_in[4];
    const float* ad1 = (const float*)d_in[5];
    const float* b1  = (const float*)d_in[6];
    const float* W2  = (const float*)d_in[7];
    const float* as2 = (const float*)d_in[8];
    const float* ad2 = (const float*)d_in[9];
    const float* b2  = (const float*)d_in[10];
    const float* W3  = (const float*)d_in[11];
    const float* as3 = (const float*)d_in[12];
    const float* ad3 = (const float*)d_in[13];
    const float* b3  = (const float*)d_in[14];
    const float* lw  = (const float*)d_in[15];
    const float* lb  = (const float*)d_in[16];
    float* out = (float*)d_out;

    char* p = (char*)d_ws;
    auto carve = [&](size_t bytes) -> void* {
        void* r = (void*)p;
        p += (bytes + 255) & ~(size_t)255;
        return r;
    };
    int*     off    = (int*)carve((NN + 4) * sizeof(int));
    int*     deg    = (int*)carve(NN * sizeof(int));
    int*     rank   = (int*)carve((size_t)(EE + NN) * sizeof(int));
    int*     bsum   = (int*)carve(NB * sizeof(int));
    int*     boff   = (int*)carve(NB * sizeof(int));
    int*     csr    = (int*)carve((size_t)(EE + NN) * sizeof(int));
    ushortx* aggb   = (ushortx*)carve((size_t)NN * 256 * sizeof(ushortx));  // 51.2 MB
    float*   agg1   = (float*)carve((size_t)NN * 64 * sizeof(float));       // 25.6 MB
    ushortx* xb1    = (ushortx*)carve((size_t)NN * 64 * sizeof(ushortx));   // 12.8 MB
    float*   outf   = (float*)carve((size_t)NN * 64 * sizeof(float));       // 25.6 MB
    float*   als    = (float*)carve((size_t)NN * 4 * sizeof(float));
    float*   ald    = (float*)carve((size_t)NN * 4 * sizeof(float));
    float*   va1    = (float*)carve(9 * 8 * sizeof(float));
    float*   va2    = (float*)carve(64 * 8 * sizeof(float));
    float*   va3    = (float*)carve(64 * 8 * sizeof(float));
    ushortx* wf2    = (ushortx*)carve(16384 * sizeof(ushortx));
    ushortx* wf3    = (ushortx*)carve(16384 * sizeof(ushortx));
    // xb2 aliases agg1 (agg1 dead after gemm36; xb2 first written by L2 GEMM)
    ushortx* xb2 = (ushortx*)agg1;

    hipMemsetAsync(deg, 0, NN * sizeof(int), stream);

    const int etot = EE + NN;
    const int eblocks = (etot + 255) / 256;
    hist_kernel<<<eblocks, 256, 0, stream>>>(ei, deg, rank);
    scan_blk<<<NB, 256, 0, stream>>>(deg, bsum);
    scan_mid<<<1, 128, 0, stream>>>(bsum, boff, off);
    scan_fin<<<NB, 256, 0, stream>>>(deg, boff, off);
    fill_sharded<<<2048, 256, 0, stream>>>(ei, off, rank, csr);

    prep_all<<<133, 256, 0, stream>>>(W1, as1, ad1, W2, as2, ad2, W3, as3, ad3,
                                      va1, va2, va3, wf2, wf3);

    const int ablocks = (NN + 15) / 16;    // 4 nodes/wave, 4 waves/block
    const int nblocks = (NN + 255) / 256;

    // layer 1 (fp32 exact: aggregate x, then K=36 GEMM)
    att_gemv<9><<<nblocks, 256, 0, stream>>>(x, va1, als, ald);
    aggregate_x1<<<ablocks, 256, 0, stream>>>(x, als, ald, off, csr, agg1);
    gemm36<<<2048, 256, 0, stream>>>(agg1, W1, b1, xb1);

    // layer 2
    att_gemv_b<<<nblocks, 256, 0, stream>>>(xb1, va2, als, ald);
    aggregate_xb<<<ablocks, 256, 0, stream>>>(xb1, als, ald, off, csr, aggb);
    gemm256_mfma<false><<<512, 256, 0, stream>>>(aggb, wf2, b2, xb2, nullptr);

    // layer 3 (fp32 node outputs; pooling in dedicated kernel, no atomics)
    att_gemv_b<<<nblocks, 256, 0, stream>>>(xb2, va3, als, ald);
    aggregate_xb<<<ablocks, 256, 0, stream>>>(xb2, als, ald, off, csr, aggb);
    gemm256_mfma<true><<<512, 256, 0, stream>>>(aggb, wf3, b3, nullptr, outf);

    pool_graph<<<(GG + 3) / 4, 256, 0, stream>>>(outf, batch, lw, lb, out);
}